// Round 1
// baseline (751.755 us; speedup 1.0000x reference)
//
#include <hip/hip_runtime.h>
#include <math.h>

// Problem constants (from reference)
#define N_NODES 20000
#define N_EDGES 160000
#define H 8
#define DV 32
#define D 256
#define NB 256
#define EPSV 1e-12f
#define SLOPE 0.2f

__device__ __forceinline__ unsigned f2ord(float f) {
    unsigned u = __float_as_uint(f);
    return (u & 0x80000000u) ? ~u : (u | 0x80000000u);
}
__device__ __forceinline__ float ord2f(unsigned u) {
    return __uint_as_float((u & 0x80000000u) ? (u ^ 0x80000000u) : ~u);
}
__device__ __forceinline__ float leaky(float x) { return x >= 0.f ? x : SLOPE * x; }

// ---------------- init: zero deg/cursor, init max buffers ----------------
__global__ void k_init(int* deg, int* cursor, unsigned* maxbuf, int n) {
    int i = blockIdx.x * 256 + threadIdx.x;
    if (i < n) { deg[i] = 0; cursor[i] = 0; }
    if (i == 0) { maxbuf[0] = f2ord(-INFINITY); maxbuf[1] = f2ord(-INFINITY); }
}

// ------------- fused value/nb GEMM + vs/vt epilogue -------------
// value = inp @ W_value          [N,256]
// nb    = inp @ neighbor_w + b   [N,256]
// vs[n,h] = dot(value[n,h*32:...], w_src[h]); vt likewise.
__global__ __launch_bounds__(256) void k_gemm(
    const float* __restrict__ inp, const float* __restrict__ Wv,
    const float* __restrict__ Wn, const float* __restrict__ nbb,
    const float* __restrict__ wsrc, const float* __restrict__ wtgt,
    float* __restrict__ value, float* __restrict__ nb,
    float* __restrict__ vs, float* __restrict__ vt)
{
    __shared__ float xs[8][256];
    int t = threadIdx.x;
    int row0 = blockIdx.x * 8;
#pragma unroll
    for (int r = 0; r < 8; ++r) xs[r][t] = inp[(size_t)(row0 + r) * 256 + t];
    __syncthreads();
    float accv[8] = {0,0,0,0,0,0,0,0};
    float accn[8] = {0,0,0,0,0,0,0,0};
    for (int k = 0; k < 256; ++k) {
        float wv = Wv[k * 256 + t];
        float wn = Wn[k * 256 + t];
#pragma unroll
        for (int r = 0; r < 8; ++r) {
            accv[r] = fmaf(xs[r][k], wv, accv[r]);
            accn[r] = fmaf(xs[r][k], wn, accn[r]);
        }
    }
    float bn = nbb[t];
    float ws_t = wsrc[t];  // w_src is (8,32) flat == t since h=t>>5,d=t&31
    float wt_t = wtgt[t];
    int h = t >> 5;
#pragma unroll
    for (int r = 0; r < 8; ++r) {
        value[(size_t)(row0 + r) * 256 + t] = accv[r];
        nb[(size_t)(row0 + r) * 256 + t] = accn[r] + bn;
        float pv = accv[r] * ws_t;
        float pt = accv[r] * wt_t;
#pragma unroll
        for (int off = 16; off >= 1; off >>= 1) {
            pv += __shfl_xor(pv, off, 64);
            pt += __shfl_xor(pt, off, 64);
        }
        if ((t & 31) == 0) {
            vs[(size_t)(row0 + r) * 8 + h] = pv;
            vt[(size_t)(row0 + r) * 8 + h] = pt;
        }
    }
}

// ------------- relation score tables: SA[50][8], SB[4][8] -------------
// s_rel[e,h] = SA[deprel[e]][h] + SB[deparc[e]][h]
__global__ void k_rel(const float* __restrict__ Wrel, const float* __restrict__ wrel,
                      const float* __restrict__ deprel_emb, const float* __restrict__ deparc_emb,
                      float* __restrict__ SA, float* __restrict__ SB)
{
    __shared__ float wr2[128 * 8];  // wr2[k][h] = sum_r Wrel[k, h*16+r]*wrel[h,r]
    int t = threadIdx.x;
    for (int i = t; i < 1024; i += 256) {
        int k = i >> 3, h = i & 7;
        float acc = 0.f;
        for (int r = 0; r < 16; ++r)
            acc += Wrel[k * 128 + h * 16 + r] * wrel[h * 16 + r];
        wr2[k * 8 + h] = acc;
    }
    __syncthreads();
    for (int i = t; i < 50 * 8; i += 256) {
        int d = i >> 3, h = i & 7;
        float acc = 0.f;
        for (int k = 0; k < 64; ++k) acc += deprel_emb[d * 64 + k] * wr2[k * 8 + h];
        SA[i] = acc;
    }
    for (int i = t; i < 4 * 8; i += 256) {
        int d = i >> 3, h = i & 7;
        float acc = 0.f;
        for (int k = 0; k < 64; ++k) acc += deparc_emb[d * 64 + k] * wr2[(64 + k) * 8 + h];
        SB[i] = acc;
    }
}

// ------------- per-edge scores + global maxes + degree -------------
__global__ __launch_bounds__(256) void k_scores(
    const float* __restrict__ vs, const float* __restrict__ vt,
    const float* __restrict__ SA, const float* __restrict__ SB,
    const int* __restrict__ src, const int* __restrict__ tgt,
    const int* __restrict__ deprel, const int* __restrict__ deparc,
    float* __restrict__ scores_v, float* __restrict__ scores_r,
    int* __restrict__ deg, unsigned* __restrict__ maxbuf)
{
    int e = blockIdx.x * 256 + threadIdx.x;
    float mv = -INFINITY, mr = -INFINITY;
    if (e < N_EDGES) {
        int s = src[e], t = tgt[e], dr = deprel[e], da = deparc[e];
        const float4* vs4 = (const float4*)vs;
        const float4* vt4 = (const float4*)vt;
        const float4* SA4 = (const float4*)SA;
        const float4* SB4 = (const float4*)SB;
        float4 a0 = vs4[s * 2], a1 = vs4[s * 2 + 1];
        float4 b0 = vt4[t * 2], b1 = vt4[t * 2 + 1];
        float4 ra0 = SA4[dr * 2], ra1 = SA4[dr * 2 + 1];
        float4 rb0 = SB4[da * 2], rb1 = SB4[da * 2 + 1];
        float svv[8], srr[8];
        float av[8] = {a0.x, a0.y, a0.z, a0.w, a1.x, a1.y, a1.z, a1.w};
        float bv[8] = {b0.x, b0.y, b0.z, b0.w, b1.x, b1.y, b1.z, b1.w};
        float rv[8] = {ra0.x + rb0.x, ra0.y + rb0.y, ra0.z + rb0.z, ra0.w + rb0.w,
                       ra1.x + rb1.x, ra1.y + rb1.y, ra1.z + rb1.z, ra1.w + rb1.w};
#pragma unroll
        for (int h = 0; h < 8; ++h) {
            svv[h] = leaky(av[h] + bv[h]);
            srr[h] = leaky(rv[h] + bv[h]);
            mv = fmaxf(mv, svv[h]);
            mr = fmaxf(mr, srr[h]);
        }
        float4* ov = (float4*)(scores_v + (size_t)e * 8);
        float4* orr = (float4*)(scores_r + (size_t)e * 8);
        ov[0] = make_float4(svv[0], svv[1], svv[2], svv[3]);
        ov[1] = make_float4(svv[4], svv[5], svv[6], svv[7]);
        orr[0] = make_float4(srr[0], srr[1], srr[2], srr[3]);
        orr[1] = make_float4(srr[4], srr[5], srr[6], srr[7]);
        atomicAdd(&deg[t], 1);
    }
    __shared__ float red[256];
    int tix = threadIdx.x;
    red[tix] = mv;
    __syncthreads();
    for (int s2 = 128; s2 > 0; s2 >>= 1) {
        if (tix < s2) red[tix] = fmaxf(red[tix], red[tix + s2]);
        __syncthreads();
    }
    if (tix == 0) atomicMax(maxbuf + 0, f2ord(red[0]));
    __syncthreads();
    red[tix] = mr;
    __syncthreads();
    for (int s2 = 128; s2 > 0; s2 >>= 1) {
        if (tix < s2) red[tix] = fmaxf(red[tix], red[tix + s2]);
        __syncthreads();
    }
    if (tix == 0) atomicMax(maxbuf + 1, f2ord(red[0]));
}

// ------------- exclusive prefix scan of deg -> rowptr -------------
__global__ __launch_bounds__(1024) void k_scan(const int* __restrict__ deg,
                                               int* __restrict__ rowptr, int n)
{
    __shared__ int tmp[1024];
    __shared__ int carry;
    int t = threadIdx.x;
    if (t == 0) carry = 0;
    __syncthreads();
    for (int base = 0; base < n; base += 1024) {
        int v = (base + t < n) ? deg[base + t] : 0;
        tmp[t] = v;
        __syncthreads();
        for (int off = 1; off < 1024; off <<= 1) {
            int x = (t >= off) ? tmp[t - off] : 0;
            __syncthreads();
            tmp[t] += x;
            __syncthreads();
        }
        int c = carry;
        if (base + t < n) rowptr[base + t] = c + tmp[t] - v;
        __syncthreads();
        if (t == 1023) carry = c + tmp[1023];
        __syncthreads();
    }
    if (t == 0) rowptr[n] = carry;
}

// ------------- CSR fill -------------
__global__ __launch_bounds__(256) void k_fill(const int* __restrict__ tgt,
                                              const int* __restrict__ rowptr,
                                              int* __restrict__ cursor,
                                              int* __restrict__ eidx)
{
    int e = blockIdx.x * 256 + threadIdx.x;
    if (e < N_EDGES) {
        int t = tgt[e];
        int pos = atomicAdd(&cursor[t], 1);
        eidx[rowptr[t] + pos] = e;
    }
}

// ------------- per-node aggregation + full epilogue -------------
// one wave (64 lanes) per node; 4 nodes per 256-thread block
__global__ __launch_bounds__(256) void k_agg(
    const float* __restrict__ value, const float* __restrict__ nb,
    const float* __restrict__ scores_v, const float* __restrict__ scores_r,
    const unsigned* __restrict__ maxbuf,
    const int* __restrict__ rowptr, const int* __restrict__ eidx,
    const int* __restrict__ srcArr,
    const float* __restrict__ inp, const float* __restrict__ Wp,
    const float* __restrict__ Pb, const float* __restrict__ gate_w,
    const float* __restrict__ gate_b, const float* __restrict__ final_bias,
    float* __restrict__ out)
{
    __shared__ float cat[4][512];   // [node][h*64 + d]  (d<32: out_v, d>=32: out_r)
    __shared__ float nbag[4][256];
    int tid = threadIdx.x;
    int wv = tid >> 6;
    int l = tid & 63;
    int n = blockIdx.x * 4 + wv;
    float Mv = ord2f(maxbuf[0]);
    float Mr = ord2f(maxbuf[1]);
    int beg = rowptr[n], end = rowptr[n + 1];
    int deg = end - beg;

    // pass A: denominators. lanes 0..7: denom_v[h], lanes 8..15: denom_r[h]
    float den = 0.f;
    if (l < 16) {
        int h = l & 7;
        const float* sc = (l < 8) ? scores_v : scores_r;
        float M = (l < 8) ? Mv : Mr;
        for (int j = beg; j < end; ++j) {
            int e = eidx[j];
            den += expf(sc[(size_t)e * 8 + h] - M);
        }
    }
    int hbase = l >> 5;  // 0 or 1
    float dvh[4], drh[4];
#pragma unroll
    for (int r = 0; r < 4; ++r) {
        int h = 2 * r + hbase;
        dvh[r] = __shfl(den, h, 64) + EPSV;
        drh[r] = __shfl(den, 8 + h, 64) + EPSV;
    }

    // pass B: weighted accumulation
    float av[4] = {0,0,0,0}, ar[4] = {0,0,0,0}, an[4] = {0,0,0,0};
    for (int j = beg; j < end; ++j) {
        int e = eidx[j];
        int s = srcArr[e];
        const float* vrow = value + (size_t)s * 256;
        const float* nrow = nb + (size_t)s * 256;
#pragma unroll
        for (int r = 0; r < 4; ++r) {
            int h = 2 * r + hbase;
            float wV = expf(scores_v[(size_t)e * 8 + h] - Mv) / dvh[r];
            float wR = expf(scores_r[(size_t)e * 8 + h] - Mr) / drh[r];
            float val = vrow[r * 64 + l];
            av[r] = fmaf(val, wV, av[r]);
            ar[r] = fmaf(val, wR, ar[r]);
            an[r] += nrow[r * 64 + l];
        }
    }
    float dscale = 1.0f / (float)(deg > 1 ? deg : 1);
#pragma unroll
    for (int r = 0; r < 4; ++r) {
        int i = r * 64 + l;
        int h = i >> 5, d = i & 31;
        cat[wv][h * 64 + d] = av[r];
        cat[wv][h * 64 + 32 + d] = ar[r];
        nbag[wv][i] = an[r] * dscale;
    }
    __syncthreads();

    // head_out: per lane 4 outputs (h = i>>5, o = i&31), 64-dot each
    float ho[4];
#pragma unroll
    for (int r = 0; r < 4; ++r) {
        int i = r * 64 + l;
        int h = i >> 5, o = i & 31;
        float acc = Pb[h * 32 + o];
        const float* w = Wp + (size_t)h * 2048 + o;
        const float* c = &cat[wv][h * 64];
        for (int d = 0; d < 64; ++d) acc = fmaf(c[d], w[d * 32], acc);
        ho[r] = acc;
    }

    // gate: h = l&7, chunk = l>>3 covers k = chunk*64 .. +63 of 512
    int gh = l & 7, gc = l >> 3;
    const float* xin = inp + (size_t)n * 256;
    float gp = 0.f;
    for (int j = 0; j < 64; ++j) {
        int k = gc * 64 + j;
        float x = (k < 256) ? xin[k] : nbag[wv][k - 256];
        gp = fmaf(x, gate_w[k * 8 + gh], gp);
    }
    gp += __shfl_xor(gp, 8, 64);
    gp += __shfl_xor(gp, 16, 64);
    gp += __shfl_xor(gp, 32, 64);
    float gate_full = 1.f / (1.f + expf(-(gp + gate_b[gh])));

#pragma unroll
    for (int r = 0; r < 4; ++r) {
        int i = r * 64 + l;
        int h = i >> 5;
        float g = __shfl(gate_full, h, 64);
        out[(size_t)n * 256 + i] = ho[r] * g + final_bias[i];
    }
}

extern "C" void kernel_launch(void* const* d_in, const int* in_sizes, int n_in,
                              void* d_out, int out_size, void* d_ws, size_t ws_size,
                              hipStream_t stream) {
    const float* inp         = (const float*)d_in[0];
    // d_in[1] dist_edge: unused by reference
    const float* W_value     = (const float*)d_in[2];
    const float* W_relation  = (const float*)d_in[3];
    const float* deprel_emb  = (const float*)d_in[4];
    const float* deparc_emb  = (const float*)d_in[5];
    const float* w_src       = (const float*)d_in[6];
    const float* w_tgt       = (const float*)d_in[7];
    const float* w_rel       = (const float*)d_in[8];
    const float* fpw         = (const float*)d_in[9];
    const float* fpb         = (const float*)d_in[10];
    const float* neighbor_w  = (const float*)d_in[11];
    const float* neighbor_b  = (const float*)d_in[12];
    const float* gate_w      = (const float*)d_in[13];
    const float* gate_b      = (const float*)d_in[14];
    const float* final_bias  = (const float*)d_in[15];
    const int*   edge_index  = (const int*)d_in[16];
    const int*   deprel_edge = (const int*)d_in[17];
    const int*   deparc_edge = (const int*)d_in[18];
    const int* srcArr = edge_index;
    const int* tgtArr = edge_index + N_EDGES;
    float* out = (float*)d_out;

    // workspace carve (floats)
    float* value    = (float*)d_ws;                  // 5,120,000
    float* nbuf     = value + (size_t)N_NODES * 256; // 5,120,000
    float* vs       = nbuf + (size_t)N_NODES * 256;  // 160,000
    float* vt       = vs + (size_t)N_NODES * 8;      // 160,000
    float* scores_v = vt + (size_t)N_NODES * 8;      // 1,280,000
    float* scores_r = scores_v + (size_t)N_EDGES * 8;// 1,280,000
    float* SA       = scores_r + (size_t)N_EDGES * 8;// 400
    float* SB       = SA + 400;                      // 32
    unsigned* maxbuf = (unsigned*)(SB + 32);         // 2
    int* deg    = (int*)(maxbuf + 2);                // 20,000
    int* rowptr = deg + N_NODES;                     // 20,001
    int* cursor = rowptr + (N_NODES + 1);            // 20,000
    int* eidx   = cursor + N_NODES;                  // 160,000

    k_init<<<(N_NODES + 255) / 256, 256, 0, stream>>>(deg, cursor, maxbuf, N_NODES);
    k_gemm<<<N_NODES / 8, 256, 0, stream>>>(inp, W_value, neighbor_w, neighbor_b,
                                            w_src, w_tgt, value, nbuf, vs, vt);
    k_rel<<<1, 256, 0, stream>>>(W_relation, w_rel, deprel_emb, deparc_emb, SA, SB);
    k_scores<<<N_EDGES / 256, 256, 0, stream>>>(vs, vt, SA, SB, srcArr, tgtArr,
                                                deprel_edge, deparc_edge,
                                                scores_v, scores_r, deg, maxbuf);
    k_scan<<<1, 1024, 0, stream>>>(deg, rowptr, N_NODES);
    k_fill<<<N_EDGES / 256, 256, 0, stream>>>(tgtArr, rowptr, cursor, eidx);
    k_agg<<<N_NODES / 4, 256, 0, stream>>>(value, nbuf, scores_v, scores_r, maxbuf,
                                           rowptr, eidx, srcArr, inp, fpw, fpb,
                                           gate_w, gate_b, final_bias, out);
}

// Round 2
// 466.338 us; speedup vs baseline: 1.6120x; 1.6120x over previous
//
#include <hip/hip_runtime.h>
#include <math.h>

#define N_NODES 20000
#define N_EDGES 160000
#define EPSV 1e-12f
#define SLOPE 0.2f
#define LOG2E 1.4426950408889634f

__device__ __forceinline__ unsigned f2ord(float f) {
    unsigned u = __float_as_uint(f);
    return (u & 0x80000000u) ? ~u : (u | 0x80000000u);
}
__device__ __forceinline__ float ord2f(unsigned u) {
    return __uint_as_float((u & 0x80000000u) ? (u ^ 0x80000000u) : ~u);
}
__device__ __forceinline__ float leaky(float x) { return x >= 0.f ? x : SLOPE * x; }

// ---------------- init ----------------
__global__ void k_init(int* deg, int* cursor, unsigned* maxbuf, int n) {
    int i = blockIdx.x * 256 + threadIdx.x;
    if (i < n) { deg[i] = 0; cursor[i] = 0; }
    if (i == 0) { maxbuf[0] = f2ord(-INFINITY); maxbuf[1] = f2ord(-INFINITY); }
}

// ------------- fused value/nb GEMM + vs/vt epilogue -------------
__global__ __launch_bounds__(256) void k_gemm(
    const float* __restrict__ inp, const float* __restrict__ Wv,
    const float* __restrict__ Wn, const float* __restrict__ nbb,
    const float* __restrict__ wsrc, const float* __restrict__ wtgt,
    float* __restrict__ value, float* __restrict__ nb,
    float* __restrict__ vs, float* __restrict__ vt)
{
    __shared__ float xs[8][256];
    int t = threadIdx.x;
    int row0 = blockIdx.x * 8;
#pragma unroll
    for (int r = 0; r < 8; ++r) xs[r][t] = inp[(size_t)(row0 + r) * 256 + t];
    __syncthreads();
    float accv[8] = {0,0,0,0,0,0,0,0};
    float accn[8] = {0,0,0,0,0,0,0,0};
    for (int k4 = 0; k4 < 64; ++k4) {
        float xr[8][4];
#pragma unroll
        for (int r = 0; r < 8; ++r) {
            float4 tmp = *(const float4*)&xs[r][k4 * 4];
            xr[r][0] = tmp.x; xr[r][1] = tmp.y; xr[r][2] = tmp.z; xr[r][3] = tmp.w;
        }
#pragma unroll
        for (int kk = 0; kk < 4; ++kk) {
            int k = k4 * 4 + kk;
            float wv = Wv[k * 256 + t];
            float wn = Wn[k * 256 + t];
#pragma unroll
            for (int r = 0; r < 8; ++r) {
                accv[r] = fmaf(xr[r][kk], wv, accv[r]);
                accn[r] = fmaf(xr[r][kk], wn, accn[r]);
            }
        }
    }
    float bn = nbb[t];
    float ws_t = wsrc[t];
    float wt_t = wtgt[t];
    int h = t >> 5;
#pragma unroll
    for (int r = 0; r < 8; ++r) {
        value[(size_t)(row0 + r) * 256 + t] = accv[r];
        nb[(size_t)(row0 + r) * 256 + t] = accn[r] + bn;
        float pv = accv[r] * ws_t;
        float pt = accv[r] * wt_t;
#pragma unroll
        for (int off = 16; off >= 1; off >>= 1) {
            pv += __shfl_xor(pv, off, 64);
            pt += __shfl_xor(pt, off, 64);
        }
        if ((t & 31) == 0) {
            vs[(size_t)(row0 + r) * 8 + h] = pv;
            vt[(size_t)(row0 + r) * 8 + h] = pt;
        }
    }
}

// ------------- gate partials: g1[n,h]=inp[n]·gw1[:,h], g2[n,h]=nb[n]·gw2[:,h] -------------
__global__ __launch_bounds__(256) void k_gate(
    const float* __restrict__ inp, const float* __restrict__ nb,
    const float* __restrict__ gw, float* __restrict__ g1, float* __restrict__ g2)
{
    int t = threadIdx.x, lane = t & 63, wv = t >> 6;
    int n = blockIdx.x * 4 + wv;
    const float* x = inp + (size_t)n * 256;
    const float* nbv = nb + (size_t)n * 256;
    int h = lane & 7, c = lane >> 3;  // c: chunk of 32
    float p1 = 0.f, p2 = 0.f;
    for (int j = 0; j < 32; ++j) {
        int k = c * 32 + j;
        p1 = fmaf(x[k], gw[k * 8 + h], p1);
        p2 = fmaf(nbv[k], gw[(256 + k) * 8 + h], p2);
    }
    p1 += __shfl_xor(p1, 8, 64);  p2 += __shfl_xor(p2, 8, 64);
    p1 += __shfl_xor(p1, 16, 64); p2 += __shfl_xor(p2, 16, 64);
    p1 += __shfl_xor(p1, 32, 64); p2 += __shfl_xor(p2, 32, 64);
    if (lane < 8) { g1[(size_t)n * 8 + lane] = p1; g2[(size_t)n * 8 + lane] = p2; }
}

// ------------- relation score tables -------------
__global__ void k_rel(const float* __restrict__ Wrel, const float* __restrict__ wrel,
                      const float* __restrict__ deprel_emb, const float* __restrict__ deparc_emb,
                      float* __restrict__ SA, float* __restrict__ SB)
{
    __shared__ float wr2[128 * 8];
    int t = threadIdx.x;
    for (int i = t; i < 1024; i += 256) {
        int k = i >> 3, h = i & 7;
        float acc = 0.f;
        for (int r = 0; r < 16; ++r)
            acc += Wrel[k * 128 + h * 16 + r] * wrel[h * 16 + r];
        wr2[k * 8 + h] = acc;
    }
    __syncthreads();
    for (int i = t; i < 50 * 8; i += 256) {
        int d = i >> 3, h = i & 7;
        float acc = 0.f;
        for (int k = 0; k < 64; ++k) acc += deprel_emb[d * 64 + k] * wr2[k * 8 + h];
        SA[i] = acc;
    }
    for (int i = t; i < 4 * 8; i += 256) {
        int d = i >> 3, h = i & 7;
        float acc = 0.f;
        for (int k = 0; k < 64; ++k) acc += deparc_emb[d * 64 + k] * wr2[(64 + k) * 8 + h];
        SB[i] = acc;
    }
}

// ------------- per-edge scores (interleaved [E][16]) + global maxes + degree -------------
__global__ __launch_bounds__(256) void k_scores(
    const float* __restrict__ vs, const float* __restrict__ vt,
    const float* __restrict__ SA, const float* __restrict__ SB,
    const int* __restrict__ src, const int* __restrict__ tgt,
    const int* __restrict__ deprel, const int* __restrict__ deparc,
    float* __restrict__ sc, int* __restrict__ deg, unsigned* __restrict__ maxbuf)
{
    int e = blockIdx.x * 256 + threadIdx.x;
    float mv = -INFINITY, mr = -INFINITY;
    int s = src[e], t = tgt[e], dr = deprel[e], da = deparc[e];
    const float4* vs4 = (const float4*)vs;
    const float4* vt4 = (const float4*)vt;
    const float4* SA4 = (const float4*)SA;
    const float4* SB4 = (const float4*)SB;
    float4 a0 = vs4[s * 2], a1 = vs4[s * 2 + 1];
    float4 b0 = vt4[t * 2], b1 = vt4[t * 2 + 1];
    float4 ra0 = SA4[dr * 2], ra1 = SA4[dr * 2 + 1];
    float4 rb0 = SB4[da * 2], rb1 = SB4[da * 2 + 1];
    float svv[8], srr[8];
    float av[8] = {a0.x, a0.y, a0.z, a0.w, a1.x, a1.y, a1.z, a1.w};
    float bv[8] = {b0.x, b0.y, b0.z, b0.w, b1.x, b1.y, b1.z, b1.w};
    float rv[8] = {ra0.x + rb0.x, ra0.y + rb0.y, ra0.z + rb0.z, ra0.w + rb0.w,
                   ra1.x + rb1.x, ra1.y + rb1.y, ra1.z + rb1.z, ra1.w + rb1.w};
#pragma unroll
    for (int h = 0; h < 8; ++h) {
        svv[h] = leaky(av[h] + bv[h]);
        srr[h] = leaky(rv[h] + bv[h]);
        mv = fmaxf(mv, svv[h]);
        mr = fmaxf(mr, srr[h]);
    }
    float4* o4 = (float4*)(sc + (size_t)e * 16);
    o4[0] = make_float4(svv[0], svv[1], svv[2], svv[3]);
    o4[1] = make_float4(svv[4], svv[5], svv[6], svv[7]);
    o4[2] = make_float4(srr[0], srr[1], srr[2], srr[3]);
    o4[3] = make_float4(srr[4], srr[5], srr[6], srr[7]);
    atomicAdd(&deg[t], 1);
#pragma unroll
    for (int off = 32; off >= 1; off >>= 1) {
        mv = fmaxf(mv, __shfl_xor(mv, off, 64));
        mr = fmaxf(mr, __shfl_xor(mr, off, 64));
    }
    if ((threadIdx.x & 63) == 0) {
        atomicMax(maxbuf + 0, f2ord(mv));
        atomicMax(maxbuf + 1, f2ord(mr));
    }
}

// ------------- prefix scan (shfl-based) -------------
__global__ __launch_bounds__(1024) void k_scan(const int* __restrict__ deg,
                                               int* __restrict__ rowptr, int n)
{
    __shared__ int wbase[16];
    __shared__ int carryS;
    int t = threadIdx.x, lane = t & 63, w = t >> 6;
    if (t == 0) carryS = 0;
    __syncthreads();
    for (int base = 0; base < n; base += 1024) {
        int i = base + t;
        int v = (i < n) ? deg[i] : 0;
        int s = v;
#pragma unroll
        for (int off = 1; off < 64; off <<= 1) {
            int x = __shfl_up(s, off, 64);
            if (lane >= off) s += x;
        }
        if (lane == 63) wbase[w] = s;
        __syncthreads();
        if (t < 16) {
            int x = wbase[t];
            int ss = x;
#pragma unroll
            for (int off = 1; off < 16; off <<= 1) {
                int y = __shfl_up(ss, off, 16);
                if ((t & 15) >= off) ss += y;
            }
            wbase[t] = ss - x;  // exclusive
        }
        __syncthreads();
        int c = carryS;
        int excl = c + wbase[w] + s - v;
        if (i < n) rowptr[i] = excl;
        __syncthreads();
        if (t == 1023) carryS = excl + v;
        __syncthreads();
    }
    if (t == 0) rowptr[n] = carryS;
}

// ------------- CSR fill -------------
__global__ __launch_bounds__(256) void k_fill(const int* __restrict__ tgt,
                                              const int* __restrict__ rowptr,
                                              int* __restrict__ cursor,
                                              int* __restrict__ eidx)
{
    int e = blockIdx.x * 256 + threadIdx.x;
    int t = tgt[e];
    int pos = atomicAdd(&cursor[t], 1);
    eidx[rowptr[t] + pos] = e;
}

// ------------- per-node aggregation + epilogue; one wave per node -------------
__global__ __launch_bounds__(256) void k_agg(
    const float* __restrict__ value, const float* __restrict__ sc,
    const float* __restrict__ g2, const float* __restrict__ g1,
    const unsigned* __restrict__ maxbuf,
    const int* __restrict__ rowptr, const int* __restrict__ eidx,
    const int* __restrict__ srcArr,
    const float* __restrict__ Wp, const float* __restrict__ Pb,
    const float* __restrict__ gate_b, const float* __restrict__ final_bias,
    float* __restrict__ out)
{
    __shared__ float cat[4][8 * 68];
    int tid = threadIdx.x, wv = tid >> 6, l = tid & 63;
    int n = blockIdx.x * 4 + wv;
    float Mv = ord2f(maxbuf[0]);
    float Mr = ord2f(maxbuf[1]);
    float msel = (l < 8) ? Mv : Mr;
    int beg = rowptr[n], end = rowptr[n + 1];
    int deg = end - beg;
    int h8 = l >> 3;
    int q = l & 7;

    float acc = 0.f;
    float4 av = make_float4(0, 0, 0, 0), ar = make_float4(0, 0, 0, 0);

    for (int base = beg; base < end; base += 64) {
        int cnt = min(64, end - base);
        int epre = 0, spre = 0;
        if (l < cnt) { epre = eidx[base + l]; spre = srcArr[epre]; }
        // prologue: edge 0 loads
        int e = __shfl(epre, 0, 64);
        int s = __shfl(spre, 0, 64);
        float raw = 0.f;
        if (l < 16) raw = sc[(size_t)e * 16 + l];
        else if (l < 24) raw = g2[(size_t)s * 8 + q];
        float4 vv = *(const float4*)(value + (size_t)s * 256 + l * 4);
        for (int j = 0; j < cnt; ++j) {
            float rawc = raw;
            float4 vc = vv;
            if (j + 1 < cnt) {
                int e1 = __shfl(epre, j + 1, 64);
                int s1 = __shfl(spre, j + 1, 64);
                raw = 0.f;
                if (l < 16) raw = sc[(size_t)e1 * 16 + l];
                else if (l < 24) raw = g2[(size_t)s1 * 8 + q];
                vv = *(const float4*)(value + (size_t)s1 * 256 + l * 4);
            }
            float tmp = (l < 16) ? exp2f((rawc - msel) * LOG2E) : rawc;
            if (l < 24) acc += tmp;
            float wV = __shfl(tmp, h8, 64);
            float wR = __shfl(tmp, 8 + h8, 64);
            av.x = fmaf(vc.x, wV, av.x); av.y = fmaf(vc.y, wV, av.y);
            av.z = fmaf(vc.z, wV, av.z); av.w = fmaf(vc.w, wV, av.w);
            ar.x = fmaf(vc.x, wR, ar.x); ar.y = fmaf(vc.y, wR, ar.y);
            ar.z = fmaf(vc.z, wR, ar.z); ar.w = fmaf(vc.w, wR, ar.w);
        }
    }
    // normalize
    float dv = __shfl(acc, h8, 64) + EPSV;
    float drn = __shfl(acc, 8 + h8, 64) + EPSV;
    float rdv = 1.f / dv, rdr = 1.f / drn;
    av.x *= rdv; av.y *= rdv; av.z *= rdv; av.w *= rdv;
    ar.x *= rdr; ar.y *= rdr; ar.z *= rdr; ar.w *= rdr;

    // stash into LDS: cat[wv][h*68 + d], d<32: out_v, d>=32: out_r
    float* cp = &cat[wv][h8 * 68 + q * 4];
    *(float4*)cp = av;
    *(float4*)(cp + 32) = ar;

    // gate
    float dscale = 1.f / (float)(deg > 1 ? deg : 1);
    float gs = __shfl(acc, 16 + q, 64);
    float gfull = 0.f;
    if (l < 8) {
        float gl = g1[(size_t)n * 8 + l] + gs * dscale + gate_b[l];
        gfull = 1.f / (1.f + exp2f(-gl * LOG2E));
    }
    float g = __shfl(gfull, h8, 64);
    __syncthreads();

    // head_out: lane computes outputs (h8, o = q*4 .. q*4+3)
    float4 ho = *(const float4*)(Pb + l * 4);
    const float* crow = &cat[wv][h8 * 68];
    const float* wrow = Wp + (size_t)h8 * 2048 + q * 4;
#pragma unroll 4
    for (int d = 0; d < 64; ++d) {
        float c = crow[d];
        float4 w4 = *(const float4*)(wrow + d * 32);
        ho.x = fmaf(c, w4.x, ho.x); ho.y = fmaf(c, w4.y, ho.y);
        ho.z = fmaf(c, w4.z, ho.z); ho.w = fmaf(c, w4.w, ho.w);
    }
    float4 fb = *(const float4*)(final_bias + l * 4);
    float4 o;
    o.x = fmaf(ho.x, g, fb.x); o.y = fmaf(ho.y, g, fb.y);
    o.z = fmaf(ho.z, g, fb.z); o.w = fmaf(ho.w, g, fb.w);
    *(float4*)(out + (size_t)n * 256 + l * 4) = o;
}

extern "C" void kernel_launch(void* const* d_in, const int* in_sizes, int n_in,
                              void* d_out, int out_size, void* d_ws, size_t ws_size,
                              hipStream_t stream) {
    const float* inp         = (const float*)d_in[0];
    const float* W_value     = (const float*)d_in[2];
    const float* W_relation  = (const float*)d_in[3];
    const float* deprel_emb  = (const float*)d_in[4];
    const float* deparc_emb  = (const float*)d_in[5];
    const float* w_src       = (const float*)d_in[6];
    const float* w_tgt       = (const float*)d_in[7];
    const float* w_rel       = (const float*)d_in[8];
    const float* fpw         = (const float*)d_in[9];
    const float* fpb         = (const float*)d_in[10];
    const float* neighbor_w  = (const float*)d_in[11];
    const float* neighbor_b  = (const float*)d_in[12];
    const float* gate_w      = (const float*)d_in[13];
    const float* gate_b      = (const float*)d_in[14];
    const float* final_bias  = (const float*)d_in[15];
    const int*   edge_index  = (const int*)d_in[16];
    const int*   deprel_edge = (const int*)d_in[17];
    const int*   deparc_edge = (const int*)d_in[18];
    const int* srcArr = edge_index;
    const int* tgtArr = edge_index + N_EDGES;
    float* out = (float*)d_out;

    // workspace carve (floats). sc overlays nb (nb dead after k_gate).
    float* value = (float*)d_ws;                      // 5,120,000
    float* nbuf  = value + (size_t)N_NODES * 256;     // 5,120,000
    float* sc    = nbuf;                              // overlay: 2,560,000
    float* g1    = nbuf + (size_t)N_NODES * 256;      // 160,000
    float* g2    = g1 + (size_t)N_NODES * 8;          // 160,000
    float* vs    = g2 + (size_t)N_NODES * 8;          // 160,000
    float* vt    = vs + (size_t)N_NODES * 8;          // 160,000
    float* SA    = vt + (size_t)N_NODES * 8;          // 400
    float* SB    = SA + 400;                          // 32
    unsigned* maxbuf = (unsigned*)(SB + 32);          // 2
    int* deg    = (int*)(maxbuf + 2);
    int* rowptr = deg + N_NODES;
    int* cursor = rowptr + (N_NODES + 1);
    int* eidx   = cursor + N_NODES;

    k_init<<<(N_NODES + 255) / 256, 256, 0, stream>>>(deg, cursor, maxbuf, N_NODES);
    k_gemm<<<N_NODES / 8, 256, 0, stream>>>(inp, W_value, neighbor_w, neighbor_b,
                                            w_src, w_tgt, value, nbuf, vs, vt);
    k_gate<<<N_NODES / 4, 256, 0, stream>>>(inp, nbuf, gate_w, g1, g2);
    k_rel<<<1, 256, 0, stream>>>(W_relation, w_rel, deprel_emb, deparc_emb, SA, SB);
    k_scores<<<N_EDGES / 256, 256, 0, stream>>>(vs, vt, SA, SB, srcArr, tgtArr,
                                                deprel_edge, deparc_edge,
                                                sc, deg, maxbuf);
    k_scan<<<1, 1024, 0, stream>>>(deg, rowptr, N_NODES);
    k_fill<<<N_EDGES / 256, 256, 0, stream>>>(tgtArr, rowptr, cursor, eidx);
    k_agg<<<N_NODES / 4, 256, 0, stream>>>(value, sc, g2, g1, maxbuf,
                                           rowptr, eidx, srcArr, fpw, fpb,
                                           gate_b, final_bias, out);
}

// Round 3
// 409.289 us; speedup vs baseline: 1.8367x; 1.1394x over previous
//
#include <hip/hip_runtime.h>
#include <math.h>

#define N_NODES 20000
#define N_EDGES 160000
#define EPSV 1e-12f
#define SLOPE 0.2f
#define LOG2E 1.4426950408889634f

__device__ __forceinline__ float leaky(float x) { return x >= 0.f ? x : SLOPE * x; }

// ------------- fused value/nb GEMM + vs/vt epilogue -------------
__global__ __launch_bounds__(256) void k_gemm(
    const float* __restrict__ inp, const float* __restrict__ Wv,
    const float* __restrict__ Wn, const float* __restrict__ nbb,
    const float* __restrict__ wsrc, const float* __restrict__ wtgt,
    float* __restrict__ value, float* __restrict__ nb,
    float* __restrict__ vs, float* __restrict__ vt)
{
    __shared__ float xs[8][256];
    int t = threadIdx.x;
    int row0 = blockIdx.x * 8;
#pragma unroll
    for (int r = 0; r < 8; ++r) xs[r][t] = inp[(size_t)(row0 + r) * 256 + t];
    __syncthreads();
    float accv[8] = {0,0,0,0,0,0,0,0};
    float accn[8] = {0,0,0,0,0,0,0,0};
    for (int k4 = 0; k4 < 64; ++k4) {
        float xr[8][4];
#pragma unroll
        for (int r = 0; r < 8; ++r) {
            float4 tmp = *(const float4*)&xs[r][k4 * 4];
            xr[r][0] = tmp.x; xr[r][1] = tmp.y; xr[r][2] = tmp.z; xr[r][3] = tmp.w;
        }
#pragma unroll
        for (int kk = 0; kk < 4; ++kk) {
            int k = k4 * 4 + kk;
            float wv = Wv[k * 256 + t];
            float wn = Wn[k * 256 + t];
#pragma unroll
            for (int r = 0; r < 8; ++r) {
                accv[r] = fmaf(xr[r][kk], wv, accv[r]);
                accn[r] = fmaf(xr[r][kk], wn, accn[r]);
            }
        }
    }
    float bn = nbb[t];
    float ws_t = wsrc[t];
    float wt_t = wtgt[t];
    int h = t >> 5;
#pragma unroll
    for (int r = 0; r < 8; ++r) {
        value[(size_t)(row0 + r) * 256 + t] = accv[r];
        nb[(size_t)(row0 + r) * 256 + t] = accn[r] + bn;
        float pv = accv[r] * ws_t;
        float pt = accv[r] * wt_t;
#pragma unroll
        for (int off = 16; off >= 1; off >>= 1) {
            pv += __shfl_xor(pv, off, 64);
            pt += __shfl_xor(pt, off, 64);
        }
        if ((t & 31) == 0) {
            vs[(size_t)(row0 + r) * 8 + h] = pv;
            vt[(size_t)(row0 + r) * 8 + h] = pt;
        }
    }
}

// ------------- gate partials -------------
__global__ __launch_bounds__(256) void k_gate(
    const float* __restrict__ inp, const float* __restrict__ nb,
    const float* __restrict__ gw, float* __restrict__ g1, float* __restrict__ g2)
{
    int t = threadIdx.x, lane = t & 63, wv = t >> 6;
    int n = blockIdx.x * 4 + wv;
    const float* x = inp + (size_t)n * 256;
    const float* nbv = nb + (size_t)n * 256;
    int h = lane & 7, c = lane >> 3;
    float p1 = 0.f, p2 = 0.f;
    for (int j = 0; j < 32; ++j) {
        int k = c * 32 + j;
        p1 = fmaf(x[k], gw[k * 8 + h], p1);
        p2 = fmaf(nbv[k], gw[(256 + k) * 8 + h], p2);
    }
    p1 += __shfl_xor(p1, 8, 64);  p2 += __shfl_xor(p2, 8, 64);
    p1 += __shfl_xor(p1, 16, 64); p2 += __shfl_xor(p2, 16, 64);
    p1 += __shfl_xor(p1, 32, 64); p2 += __shfl_xor(p2, 32, 64);
    if (lane < 8) { g1[(size_t)n * 8 + lane] = p1; g2[(size_t)n * 8 + lane] = p2; }
}

// ------------- relation score tables -------------
__global__ void k_rel(const float* __restrict__ Wrel, const float* __restrict__ wrel,
                      const float* __restrict__ deprel_emb, const float* __restrict__ deparc_emb,
                      float* __restrict__ SA, float* __restrict__ SB)
{
    __shared__ float wr2[128 * 8];
    int t = threadIdx.x;
    for (int i = t; i < 1024; i += 256) {
        int k = i >> 3, h = i & 7;
        float acc = 0.f;
        for (int r = 0; r < 16; ++r)
            acc += Wrel[k * 128 + h * 16 + r] * wrel[h * 16 + r];
        wr2[k * 8 + h] = acc;
    }
    __syncthreads();
    for (int i = t; i < 50 * 8; i += 256) {
        int d = i >> 3, h = i & 7;
        float acc = 0.f;
        for (int k = 0; k < 64; ++k) acc += deprel_emb[d * 64 + k] * wr2[k * 8 + h];
        SA[i] = acc;
    }
    for (int i = t; i < 4 * 8; i += 256) {
        int d = i >> 3, h = i & 7;
        float acc = 0.f;
        for (int k = 0; k < 64; ++k) acc += deparc_emb[d * 64 + k] * wr2[(64 + k) * 8 + h];
        SB[i] = acc;
    }
}

// ------------- degree count: 80 blocks x 250-node ranges, LDS histogram -------------
__global__ __launch_bounds__(256) void k_count(const int* __restrict__ tgt,
                                               int* __restrict__ deg)
{
    __shared__ int cnt[250];
    int tid = threadIdx.x;
    int lo = blockIdx.x * 250;
    if (tid < 250) cnt[tid] = 0;
    __syncthreads();
    const int4* t4 = (const int4*)tgt;
#pragma unroll 4
    for (int i = tid; i < N_EDGES / 4; i += 256) {
        int4 v = t4[i];
        unsigned a = (unsigned)(v.x - lo); if (a < 250u) atomicAdd(&cnt[a], 1);
        unsigned b = (unsigned)(v.y - lo); if (b < 250u) atomicAdd(&cnt[b], 1);
        unsigned c = (unsigned)(v.z - lo); if (c < 250u) atomicAdd(&cnt[c], 1);
        unsigned d = (unsigned)(v.w - lo); if (d < 250u) atomicAdd(&cnt[d], 1);
    }
    __syncthreads();
    if (tid < 250) deg[lo + tid] = cnt[tid];
}

// ------------- prefix scan (shfl-based, single block) -------------
__global__ __launch_bounds__(1024) void k_scan(const int* __restrict__ deg,
                                               int* __restrict__ rowptr, int n)
{
    __shared__ int wbase[16];
    __shared__ int carryS;
    int t = threadIdx.x, lane = t & 63, w = t >> 6;
    if (t == 0) carryS = 0;
    __syncthreads();
    for (int base = 0; base < n; base += 1024) {
        int i = base + t;
        int v = (i < n) ? deg[i] : 0;
        int s = v;
#pragma unroll
        for (int off = 1; off < 64; off <<= 1) {
            int x = __shfl_up(s, off, 64);
            if (lane >= off) s += x;
        }
        if (lane == 63) wbase[w] = s;
        __syncthreads();
        if (t < 16) {
            int x = wbase[t];
            int ss = x;
#pragma unroll
            for (int off = 1; off < 16; off <<= 1) {
                int y = __shfl_up(ss, off, 16);
                if ((t & 15) >= off) ss += y;
            }
            wbase[t] = ss - x;
        }
        __syncthreads();
        int c = carryS;
        int excl = c + wbase[w] + s - v;
        if (i < n) rowptr[i] = excl;
        __syncthreads();
        if (t == 1023) carryS = excl + v;
        __syncthreads();
    }
    if (t == 0) rowptr[n] = carryS;
}

// ------------- CSR fill: 80 blocks x 250-node ranges, LDS cursors -------------
__global__ __launch_bounds__(256) void k_fill(const int* __restrict__ tgt,
                                              const int* __restrict__ rowptr,
                                              int* __restrict__ eidx)
{
    __shared__ int cur[250];
    int tid = threadIdx.x;
    int lo = blockIdx.x * 250;
    if (tid < 250) cur[tid] = rowptr[lo + tid];
    __syncthreads();
    const int4* t4 = (const int4*)tgt;
    for (int i = tid; i < N_EDGES / 4; i += 256) {
        int4 v = t4[i];
        int e = i * 4;
        unsigned a = (unsigned)(v.x - lo); if (a < 250u) { int p = atomicAdd(&cur[a], 1); eidx[p] = e; }
        unsigned b = (unsigned)(v.y - lo); if (b < 250u) { int p = atomicAdd(&cur[b], 1); eidx[p] = e + 1; }
        unsigned c = (unsigned)(v.z - lo); if (c < 250u) { int p = atomicAdd(&cur[c], 1); eidx[p] = e + 2; }
        unsigned d = (unsigned)(v.w - lo); if (d < 250u) { int p = atomicAdd(&cur[d], 1); eidx[p] = e + 3; }
    }
}

// ------------- per-node aggregation, inline scores + epilogue; one wave per node -------------
__global__ __launch_bounds__(256) void k_agg(
    const float* __restrict__ value, const float* __restrict__ vs,
    const float* __restrict__ vt, const float* __restrict__ SA,
    const float* __restrict__ SB, const float* __restrict__ g2,
    const float* __restrict__ g1,
    const int* __restrict__ rowptr, const int* __restrict__ eidx,
    const int* __restrict__ srcArr, const int* __restrict__ deprel,
    const int* __restrict__ deparc,
    const float* __restrict__ Wp, const float* __restrict__ Pb,
    const float* __restrict__ gate_b, const float* __restrict__ final_bias,
    float* __restrict__ out)
{
    __shared__ float cat[4][8 * 68];
    int tid = threadIdx.x, wv = tid >> 6, l = tid & 63;
    int n = blockIdx.x * 4 + wv;
    int beg = rowptr[n], end = rowptr[n + 1];
    int deg = end - beg;
    int h8 = l >> 3;
    int q = l & 7;
    float vtq = vt[(size_t)n * 8 + q];

    float acc = 0.f;
    float4 av = make_float4(0, 0, 0, 0), ar = make_float4(0, 0, 0, 0);

    for (int base = beg; base < end; base += 64) {
        int cnt = min(64, end - base);
        int epre = 0, spre = 0, drpre = 0, dapre = 0;
        if (l < cnt) {
            epre = eidx[base + l];
            spre = srcArr[epre];
            drpre = deprel[epre];
            dapre = deparc[epre];
        }
        // prologue: edge 0 loads
        int s0 = __shfl(spre, 0, 64);
        int dr0 = __shfl(drpre, 0, 64);
        int da0 = __shfl(dapre, 0, 64);
        float raw = 0.f;
        if (l < 8)       raw = vs[(size_t)s0 * 8 + q];
        else if (l < 16) raw = SA[dr0 * 8 + q];
        else if (l < 24) raw = g2[(size_t)s0 * 8 + q];
        else if (l < 32) raw = SB[da0 * 8 + q];
        float4 vv = *(const float4*)(value + (size_t)s0 * 256 + l * 4);
        for (int j = 0; j < cnt; ++j) {
            float rawc = raw;
            float4 vc = vv;
            if (j + 1 < cnt) {
                int s1 = __shfl(spre, j + 1, 64);
                int dr1 = __shfl(drpre, j + 1, 64);
                int da1 = __shfl(dapre, j + 1, 64);
                if (l < 8)       raw = vs[(size_t)s1 * 8 + q];
                else if (l < 16) raw = SA[dr1 * 8 + q];
                else if (l < 24) raw = g2[(size_t)s1 * 8 + q];
                else if (l < 32) raw = SB[da1 * 8 + q];
                vv = *(const float4*)(value + (size_t)s1 * 256 + l * 4);
            }
            // scores: lanes 0-7 value-attn (vs+vt), lanes 8-15 rel-attn (SA+SB+vt)
            float sb = __shfl(rawc, 24 + q, 64);
            float bv = (l < 8) ? (rawc + vtq) : (rawc + sb + vtq);
            float tmp = (l < 16) ? exp2f(leaky(bv) * LOG2E) : rawc;
            if (l < 24) acc += tmp;
            float wV = __shfl(tmp, h8, 64);
            float wR = __shfl(tmp, 8 + h8, 64);
            av.x = fmaf(vc.x, wV, av.x); av.y = fmaf(vc.y, wV, av.y);
            av.z = fmaf(vc.z, wV, av.z); av.w = fmaf(vc.w, wV, av.w);
            ar.x = fmaf(vc.x, wR, ar.x); ar.y = fmaf(vc.y, wR, ar.y);
            ar.z = fmaf(vc.z, wR, ar.z); ar.w = fmaf(vc.w, wR, ar.w);
        }
    }
    // normalize (EPS in denominator matches reference; deg-0 -> exact 0)
    float dv = __shfl(acc, h8, 64) + EPSV;
    float drn = __shfl(acc, 8 + h8, 64) + EPSV;
    float rdv = 1.f / dv, rdr = 1.f / drn;
    av.x *= rdv; av.y *= rdv; av.z *= rdv; av.w *= rdv;
    ar.x *= rdr; ar.y *= rdr; ar.z *= rdr; ar.w *= rdr;

    float* cp = &cat[wv][h8 * 68 + q * 4];
    *(float4*)cp = av;
    *(float4*)(cp + 32) = ar;

    // gate
    float dscale = 1.f / (float)(deg > 1 ? deg : 1);
    float gs = __shfl(acc, 16 + q, 64);
    float gfull = 0.f;
    if (l < 8) {
        float gl = g1[(size_t)n * 8 + l] + gs * dscale + gate_b[l];
        gfull = 1.f / (1.f + exp2f(-gl * LOG2E));
    }
    float g = __shfl(gfull, h8, 64);
    __syncthreads();

    // head_out: lane computes outputs (h8, o = q*4 .. q*4+3)
    float4 ho = *(const float4*)(Pb + l * 4);
    const float* crow = &cat[wv][h8 * 68];
    const float* wrow = Wp + (size_t)h8 * 2048 + q * 4;
#pragma unroll 4
    for (int d = 0; d < 64; ++d) {
        float c = crow[d];
        float4 w4 = *(const float4*)(wrow + d * 32);
        ho.x = fmaf(c, w4.x, ho.x); ho.y = fmaf(c, w4.y, ho.y);
        ho.z = fmaf(c, w4.z, ho.z); ho.w = fmaf(c, w4.w, ho.w);
    }
    float4 fb = *(const float4*)(final_bias + l * 4);
    float4 o;
    o.x = fmaf(ho.x, g, fb.x); o.y = fmaf(ho.y, g, fb.y);
    o.z = fmaf(ho.z, g, fb.z); o.w = fmaf(ho.w, g, fb.w);
    *(float4*)(out + (size_t)n * 256 + l * 4) = o;
}

extern "C" void kernel_launch(void* const* d_in, const int* in_sizes, int n_in,
                              void* d_out, int out_size, void* d_ws, size_t ws_size,
                              hipStream_t stream) {
    const float* inp         = (const float*)d_in[0];
    const float* W_value     = (const float*)d_in[2];
    const float* W_relation  = (const float*)d_in[3];
    const float* deprel_emb  = (const float*)d_in[4];
    const float* deparc_emb  = (const float*)d_in[5];
    const float* w_src       = (const float*)d_in[6];
    const float* w_tgt       = (const float*)d_in[7];
    const float* w_rel       = (const float*)d_in[8];
    const float* fpw         = (const float*)d_in[9];
    const float* fpb         = (const float*)d_in[10];
    const float* neighbor_w  = (const float*)d_in[11];
    const float* neighbor_b  = (const float*)d_in[12];
    const float* gate_w      = (const float*)d_in[13];
    const float* gate_b      = (const float*)d_in[14];
    const float* final_bias  = (const float*)d_in[15];
    const int*   edge_index  = (const int*)d_in[16];
    const int*   deprel_edge = (const int*)d_in[17];
    const int*   deparc_edge = (const int*)d_in[18];
    const int* srcArr = edge_index;
    const int* tgtArr = edge_index + N_EDGES;
    float* out = (float*)d_out;

    // workspace carve (floats)
    float* value = (float*)d_ws;                      // 5,120,000
    float* nbuf  = value + (size_t)N_NODES * 256;     // 5,120,000
    float* g1    = nbuf + (size_t)N_NODES * 256;      // 160,000
    float* g2    = g1 + (size_t)N_NODES * 8;          // 160,000
    float* vs    = g2 + (size_t)N_NODES * 8;          // 160,000
    float* vt    = vs + (size_t)N_NODES * 8;          // 160,000
    float* SA    = vt + (size_t)N_NODES * 8;          // 400
    float* SB    = SA + 400;                          // 32
    int* deg    = (int*)(SB + 32);                    // 20,000
    int* rowptr = deg + N_NODES;                      // 20,001
    int* eidx   = rowptr + (N_NODES + 1);             // 160,000

    k_gemm<<<N_NODES / 8, 256, 0, stream>>>(inp, W_value, neighbor_w, neighbor_b,
                                            w_src, w_tgt, value, nbuf, vs, vt);
    k_gate<<<N_NODES / 4, 256, 0, stream>>>(inp, nbuf, gate_w, g1, g2);
    k_rel<<<1, 256, 0, stream>>>(W_relation, w_rel, deprel_emb, deparc_emb, SA, SB);
    k_count<<<80, 256, 0, stream>>>(tgtArr, deg);
    k_scan<<<1, 1024, 0, stream>>>(deg, rowptr, N_NODES);
    k_fill<<<80, 256, 0, stream>>>(tgtArr, rowptr, eidx);
    k_agg<<<N_NODES / 4, 256, 0, stream>>>(value, vs, vt, SA, SB, g2, g1,
                                           rowptr, eidx, srcArr,
                                           deprel_edge, deparc_edge,
                                           fpw, fpb, gate_b, final_bias, out);
}

// Round 4
// 348.099 us; speedup vs baseline: 2.1596x; 1.1758x over previous
//
#include <hip/hip_runtime.h>
#include <math.h>

#define N_NODES 20000
#define N_EDGES 160000
#define EPSV 1e-12f
#define SLOPE 0.2f
#define LOG2E 1.4426950408889634f

__device__ __forceinline__ float leaky(float x) { return x >= 0.f ? x : SLOPE * x; }

__device__ __forceinline__ unsigned short cvt_bf16(float f) {
    unsigned u = __float_as_uint(f);
    u = (u + 0x7FFFu + ((u >> 16) & 1u)) >> 16;
    return (unsigned short)u;
}
__device__ __forceinline__ unsigned pk2(float a, float b) {
    return (unsigned)cvt_bf16(a) | ((unsigned)cvt_bf16(b) << 16);
}

typedef __attribute__((ext_vector_type(8))) short bf16x8;
typedef __attribute__((ext_vector_type(4))) float f32x4;

// ------------- fold weights into Bt[320][256] bf16 (B^T layout: Bt[n][k]) -------------
// n<256: W_value col n. n=256+h: vs-fold. 264+h: vt-fold. 272+h: gw1. 280+h: Wn@gw2. 288+: zero.
__global__ __launch_bounds__(256) void k_fold(
    const float* __restrict__ Wv, const float* __restrict__ Wn,
    const float* __restrict__ nbb, const float* __restrict__ wsrc,
    const float* __restrict__ wtgt, const float* __restrict__ gw,
    unsigned short* __restrict__ Bt, float* __restrict__ bg2)
{
    int k = threadIdx.x;
    int b = blockIdx.x;
    if (b < 256) {
        Bt[b * 256 + k] = cvt_bf16(Wv[k * 256 + b]);
    } else if (b < 264) {
        int h = b - 256;
        float a_vs = 0.f, a_vt = 0.f, a_ng = 0.f;
        for (int d = 0; d < 32; ++d) {
            float w = Wv[k * 256 + h * 32 + d];
            a_vs = fmaf(w, wsrc[h * 32 + d], a_vs);
            a_vt = fmaf(w, wtgt[h * 32 + d], a_vt);
        }
        for (int j = 0; j < 256; ++j)
            a_ng = fmaf(Wn[k * 256 + j], gw[(256 + j) * 8 + h], a_ng);
        Bt[(256 + h) * 256 + k] = cvt_bf16(a_vs);
        Bt[(264 + h) * 256 + k] = cvt_bf16(a_vt);
        Bt[(272 + h) * 256 + k] = cvt_bf16(gw[k * 8 + h]);
        Bt[(280 + h) * 256 + k] = cvt_bf16(a_ng);
        if (k == 0) {
            float s = 0.f;
            for (int j = 0; j < 256; ++j) s = fmaf(nbb[j], gw[(256 + j) * 8 + h], s);
            bg2[h] = s;
        }
    } else {
        int n0 = 288 + (b - 264) * 4;
        for (int i = 0; i < 4; ++i) Bt[(n0 + i) * 256 + k] = 0;
    }
}

// ------------- MFMA GEMM: [20000x256] @ Bt^T -> value + vs/vt/g1/g2 -------------
// Block: 16 rows, 4 waves x 5 N-tiles of 16 = 320 cols. Inline fp32->bf16 A conversion.
__global__ __launch_bounds__(256) void k_mfma(
    const float* __restrict__ inp, const unsigned short* __restrict__ Bt,
    const float* __restrict__ bg2, float* __restrict__ value,
    float* __restrict__ vs, float* __restrict__ vt,
    float* __restrict__ g1, float* __restrict__ g2)
{
    int tid = threadIdx.x;
    int wave = tid >> 6, lane = tid & 63;
    int quad = lane >> 4, l16 = lane & 15;
    int row0 = blockIdx.x * 16;
    const float* arow = inp + (size_t)(row0 + l16) * 256;
    bf16x8 afr[8];
#pragma unroll
    for (int kk = 0; kk < 8; ++kk) {
        float4 f0 = *(const float4*)(arow + kk * 32 + quad * 8);
        float4 f1 = *(const float4*)(arow + kk * 32 + quad * 8 + 4);
        union { unsigned u[4]; bf16x8 v; } cv;
        cv.u[0] = pk2(f0.x, f0.y); cv.u[1] = pk2(f0.z, f0.w);
        cv.u[2] = pk2(f1.x, f1.y); cv.u[3] = pk2(f1.z, f1.w);
        afr[kk] = cv.v;
    }
    f32x4 acc[5] = {};
    const unsigned short* bbase = Bt + (size_t)(wave * 80 + l16) * 256 + quad * 8;
#pragma unroll
    for (int kk = 0; kk < 8; ++kk) {
#pragma unroll
        for (int t = 0; t < 5; ++t) {
            bf16x8 bf = *(const bf16x8*)(bbase + t * 16 * 256 + kk * 32);
            acc[t] = __builtin_amdgcn_mfma_f32_16x16x32_bf16(afr[kk], bf, acc[t], 0, 0, 0);
        }
    }
#pragma unroll
    for (int t = 0; t < 5; ++t) {
        int n = wave * 80 + t * 16 + l16;
#pragma unroll
        for (int r = 0; r < 4; ++r) {
            int row = row0 + quad * 4 + r;
            float v = acc[t][r];
            if (n < 256) {
                value[(size_t)row * 256 + n] = v;
            } else if (n < 288) {
                int c2 = n - 256, which = c2 >> 3, h = c2 & 7;
                if (which == 3) v += bg2[h];
                float* dst = (which == 0) ? vs : (which == 1) ? vt : (which == 2) ? g1 : g2;
                dst[(size_t)row * 8 + h] = v;
            }
        }
    }
}

// ------------- relation score tables -------------
__global__ void k_rel(const float* __restrict__ Wrel, const float* __restrict__ wrel,
                      const float* __restrict__ deprel_emb, const float* __restrict__ deparc_emb,
                      float* __restrict__ SA, float* __restrict__ SB)
{
    __shared__ float wr2[128 * 8];
    int t = threadIdx.x;
    for (int i = t; i < 1024; i += 256) {
        int k = i >> 3, h = i & 7;
        float acc = 0.f;
        for (int r = 0; r < 16; ++r)
            acc += Wrel[k * 128 + h * 16 + r] * wrel[h * 16 + r];
        wr2[k * 8 + h] = acc;
    }
    __syncthreads();
    for (int i = t; i < 50 * 8; i += 256) {
        int d = i >> 3, h = i & 7;
        float acc = 0.f;
        for (int k = 0; k < 64; ++k) acc += deprel_emb[d * 64 + k] * wr2[k * 8 + h];
        SA[i] = acc;
    }
    for (int i = t; i < 4 * 8; i += 256) {
        int d = i >> 3, h = i & 7;
        float acc = 0.f;
        for (int k = 0; k < 64; ++k) acc += deparc_emb[d * 64 + k] * wr2[(64 + k) * 8 + h];
        SB[i] = acc;
    }
}

// ------------- degree count: 80 blocks x 250-node ranges, LDS histogram -------------
__global__ __launch_bounds__(256) void k_count(const int* __restrict__ tgt,
                                               int* __restrict__ deg)
{
    __shared__ int cnt[250];
    int tid = threadIdx.x;
    int lo = blockIdx.x * 250;
    if (tid < 250) cnt[tid] = 0;
    __syncthreads();
    const int4* t4 = (const int4*)tgt;
#pragma unroll 4
    for (int i = tid; i < N_EDGES / 4; i += 256) {
        int4 v = t4[i];
        unsigned a = (unsigned)(v.x - lo); if (a < 250u) atomicAdd(&cnt[a], 1);
        unsigned b = (unsigned)(v.y - lo); if (b < 250u) atomicAdd(&cnt[b], 1);
        unsigned c = (unsigned)(v.z - lo); if (c < 250u) atomicAdd(&cnt[c], 1);
        unsigned d = (unsigned)(v.w - lo); if (d < 250u) atomicAdd(&cnt[d], 1);
    }
    __syncthreads();
    if (tid < 250) deg[lo + tid] = cnt[tid];
}

// ------------- prefix scan -------------
__global__ __launch_bounds__(1024) void k_scan(const int* __restrict__ deg,
                                               int* __restrict__ rowptr, int n)
{
    __shared__ int wbase[16];
    __shared__ int carryS;
    int t = threadIdx.x, lane = t & 63, w = t >> 6;
    if (t == 0) carryS = 0;
    __syncthreads();
    for (int base = 0; base < n; base += 1024) {
        int i = base + t;
        int v = (i < n) ? deg[i] : 0;
        int s = v;
#pragma unroll
        for (int off = 1; off < 64; off <<= 1) {
            int x = __shfl_up(s, off, 64);
            if (lane >= off) s += x;
        }
        if (lane == 63) wbase[w] = s;
        __syncthreads();
        if (t < 16) {
            int x = wbase[t];
            int ss = x;
#pragma unroll
            for (int off = 1; off < 16; off <<= 1) {
                int y = __shfl_up(ss, off, 16);
                if ((t & 15) >= off) ss += y;
            }
            wbase[t] = ss - x;
        }
        __syncthreads();
        int c = carryS;
        int excl = c + wbase[w] + s - v;
        if (i < n) rowptr[i] = excl;
        __syncthreads();
        if (t == 1023) carryS = excl + v;
        __syncthreads();
    }
    if (t == 0) rowptr[n] = carryS;
}

// ------------- CSR fill -------------
__global__ __launch_bounds__(256) void k_fill(const int* __restrict__ tgt,
                                              const int* __restrict__ rowptr,
                                              int* __restrict__ eidx)
{
    __shared__ int cur[250];
    int tid = threadIdx.x;
    int lo = blockIdx.x * 250;
    if (tid < 250) cur[tid] = rowptr[lo + tid];
    __syncthreads();
    const int4* t4 = (const int4*)tgt;
    for (int i = tid; i < N_EDGES / 4; i += 256) {
        int4 v = t4[i];
        int e = i * 4;
        unsigned a = (unsigned)(v.x - lo); if (a < 250u) { int p = atomicAdd(&cur[a], 1); eidx[p] = e; }
        unsigned b = (unsigned)(v.y - lo); if (b < 250u) { int p = atomicAdd(&cur[b], 1); eidx[p] = e + 1; }
        unsigned c = (unsigned)(v.z - lo); if (c < 250u) { int p = atomicAdd(&cur[c], 1); eidx[p] = e + 2; }
        unsigned d = (unsigned)(v.w - lo); if (d < 250u) { int p = atomicAdd(&cur[d], 1); eidx[p] = e + 3; }
    }
}

// ------------- per-node aggregation, inline scores + shared-Wp epilogue -------------
__global__ __launch_bounds__(256) void k_agg(
    const float* __restrict__ value, const float* __restrict__ vs,
    const float* __restrict__ vt, const float* __restrict__ SA,
    const float* __restrict__ SB, const float* __restrict__ g2,
    const float* __restrict__ g1,
    const int* __restrict__ rowptr, const int* __restrict__ eidx,
    const int* __restrict__ srcArr, const int* __restrict__ deprel,
    const int* __restrict__ deparc,
    const float* __restrict__ Wp, const float* __restrict__ Pb,
    const float* __restrict__ gate_b, const float* __restrict__ final_bias,
    float* __restrict__ out)
{
    __shared__ float cat[4][548];   // stride 548: +4 banks per node, 16B-aligned
    __shared__ float gate_lds[4][8];
    int tid = threadIdx.x, wv = tid >> 6, l = tid & 63;
    int n = blockIdx.x * 4 + wv;
    int beg = rowptr[n], end = rowptr[n + 1];
    int deg = end - beg;
    int h8 = l >> 3;
    int q = l & 7;
    float vtq = vt[(size_t)n * 8 + q];

    float acc = 0.f;
    float4 av = make_float4(0, 0, 0, 0), ar = make_float4(0, 0, 0, 0);

    for (int base = beg; base < end; base += 64) {
        int cnt = min(64, end - base);
        int epre = 0, spre = 0, drpre = 0, dapre = 0;
        if (l < cnt) {
            epre = eidx[base + l];
            spre = srcArr[epre];
            drpre = deprel[epre];
            dapre = deparc[epre];
        }
        int s0 = __shfl(spre, 0, 64);
        int dr0 = __shfl(drpre, 0, 64);
        int da0 = __shfl(dapre, 0, 64);
        float raw = 0.f;
        if (l < 8)       raw = vs[(size_t)s0 * 8 + q];
        else if (l < 16) raw = SA[dr0 * 8 + q];
        else if (l < 24) raw = g2[(size_t)s0 * 8 + q];
        else if (l < 32) raw = SB[da0 * 8 + q];
        float4 vv = *(const float4*)(value + (size_t)s0 * 256 + l * 4);
        for (int j = 0; j < cnt; ++j) {
            float rawc = raw;
            float4 vc = vv;
            if (j + 1 < cnt) {
                int s1 = __shfl(spre, j + 1, 64);
                int dr1 = __shfl(drpre, j + 1, 64);
                int da1 = __shfl(dapre, j + 1, 64);
                if (l < 8)       raw = vs[(size_t)s1 * 8 + q];
                else if (l < 16) raw = SA[dr1 * 8 + q];
                else if (l < 24) raw = g2[(size_t)s1 * 8 + q];
                else if (l < 32) raw = SB[da1 * 8 + q];
                vv = *(const float4*)(value + (size_t)s1 * 256 + l * 4);
            }
            float sb = __shfl(rawc, 24 + q, 64);
            float bv = (l < 8) ? (rawc + vtq) : (rawc + sb + vtq);
            float tmp = (l < 16) ? exp2f(leaky(bv) * LOG2E) : rawc;
            if (l < 24) acc += tmp;
            float wV = __shfl(tmp, h8, 64);
            float wR = __shfl(tmp, 8 + h8, 64);
            av.x = fmaf(vc.x, wV, av.x); av.y = fmaf(vc.y, wV, av.y);
            av.z = fmaf(vc.z, wV, av.z); av.w = fmaf(vc.w, wV, av.w);
            ar.x = fmaf(vc.x, wR, ar.x); ar.y = fmaf(vc.y, wR, ar.y);
            ar.z = fmaf(vc.z, wR, ar.z); ar.w = fmaf(vc.w, wR, ar.w);
        }
    }
    float dv = __shfl(acc, h8, 64) + EPSV;
    float drn = __shfl(acc, 8 + h8, 64) + EPSV;
    float rdv = 1.f / dv, rdr = 1.f / drn;
    av.x *= rdv; av.y *= rdv; av.z *= rdv; av.w *= rdv;
    ar.x *= rdr; ar.y *= rdr; ar.z *= rdr; ar.w *= rdr;

    float* cp = &cat[wv][h8 * 68 + q * 4];
    *(float4*)cp = av;
    *(float4*)(cp + 32) = ar;

    float dscale = 1.f / (float)(deg > 1 ? deg : 1);
    float gs = __shfl(acc, 16 + q, 64);
    if (l < 8) {
        float gl = g1[(size_t)n * 8 + l] + gs * dscale + gate_b[l];
        gate_lds[wv][l] = 1.f / (1.f + exp2f(-gl * LOG2E));
    }
    __syncthreads();

    // epilogue: thread -> (node nd, output group oi); 4 nodes share each Wp read
    int nd = tid & 3, oi = tid >> 2;
    int h = oi >> 3, qq = oi & 7;
    float4 ho = *(const float4*)(Pb + oi * 4);
    const float* crow = &cat[nd][h * 68];
    const float* wrow = Wp + (size_t)h * 2048 + qq * 4;
#pragma unroll 4
    for (int d = 0; d < 64; ++d) {
        float c = crow[d];
        float4 w4 = *(const float4*)(wrow + d * 32);
        ho.x = fmaf(c, w4.x, ho.x); ho.y = fmaf(c, w4.y, ho.y);
        ho.z = fmaf(c, w4.z, ho.z); ho.w = fmaf(c, w4.w, ho.w);
    }
    float g = gate_lds[nd][h];
    float4 fb = *(const float4*)(final_bias + oi * 4);
    float4 o;
    o.x = fmaf(ho.x, g, fb.x); o.y = fmaf(ho.y, g, fb.y);
    o.z = fmaf(ho.z, g, fb.z); o.w = fmaf(ho.w, g, fb.w);
    *(float4*)(out + (size_t)(blockIdx.x * 4 + nd) * 256 + oi * 4) = o;
}

extern "C" void kernel_launch(void* const* d_in, const int* in_sizes, int n_in,
                              void* d_out, int out_size, void* d_ws, size_t ws_size,
                              hipStream_t stream) {
    const float* inp         = (const float*)d_in[0];
    const float* W_value     = (const float*)d_in[2];
    const float* W_relation  = (const float*)d_in[3];
    const float* deprel_emb  = (const float*)d_in[4];
    const float* deparc_emb  = (const float*)d_in[5];
    const float* w_src       = (const float*)d_in[6];
    const float* w_tgt       = (const float*)d_in[7];
    const float* w_rel       = (const float*)d_in[8];
    const float* fpw         = (const float*)d_in[9];
    const float* fpb         = (const float*)d_in[10];
    const float* neighbor_w  = (const float*)d_in[11];
    const float* neighbor_b  = (const float*)d_in[12];
    const float* gate_w      = (const float*)d_in[13];
    const float* gate_b      = (const float*)d_in[14];
    const float* final_bias  = (const float*)d_in[15];
    const int*   edge_index  = (const int*)d_in[16];
    const int*   deprel_edge = (const int*)d_in[17];
    const int*   deparc_edge = (const int*)d_in[18];
    const int* srcArr = edge_index;
    const int* tgtArr = edge_index + N_EDGES;
    float* out = (float*)d_out;

    // workspace carve
    float* value = (float*)d_ws;                                  // 5,120,000 f
    unsigned short* Bt = (unsigned short*)(value + 5120000);      // 81,920 us
    float* bg2 = (float*)(Bt + 81920);                            // 8
    float* vs = bg2 + 8;                                          // 160,000
    float* vt = vs + 160000;
    float* g1 = vt + 160000;
    float* g2 = g1 + 160000;
    float* SA = g2 + 160000;                                      // 400
    float* SB = SA + 400;                                         // 32
    int* deg    = (int*)(SB + 32);
    int* rowptr = deg + N_NODES;
    int* eidx   = rowptr + (N_NODES + 1);

    k_fold<<<272, 256, 0, stream>>>(W_value, neighbor_w, neighbor_b,
                                    w_src, w_tgt, gate_w, Bt, bg2);
    k_rel<<<1, 256, 0, stream>>>(W_relation, w_rel, deprel_emb, deparc_emb, SA, SB);
    k_mfma<<<N_NODES / 16, 256, 0, stream>>>(inp, Bt, bg2, value, vs, vt, g1, g2);
    k_count<<<80, 256, 0, stream>>>(tgtArr, deg);
    k_scan<<<1, 1024, 0, stream>>>(deg, rowptr, N_NODES);
    k_fill<<<80, 256, 0, stream>>>(tgtArr, rowptr, eidx);
    k_agg<<<N_NODES / 4, 256, 0, stream>>>(value, vs, vt, SA, SB, g2, g1,
                                           rowptr, eidx, srcArr,
                                           deprel_edge, deparc_edge,
                                           fpw, fpb, gate_b, final_bias, out);
}

// Round 5
// 277.717 us; speedup vs baseline: 2.7069x; 1.2534x over previous
//
#include <hip/hip_runtime.h>
#include <hip/hip_fp16.h>
#include <math.h>

#define N_NODES 20000
#define N_EDGES 160000
#define EPSV 1e-12f
#define SLOPE 0.2f
#define LOG2E 1.4426950408889634f

__device__ __forceinline__ float leaky(float x) { return x >= 0.f ? x : SLOPE * x; }

__device__ __forceinline__ unsigned short cvt_bf16(float f) {
    unsigned u = __float_as_uint(f);
    u = (u + 0x7FFFu + ((u >> 16) & 1u)) >> 16;
    return (unsigned short)u;
}
__device__ __forceinline__ unsigned pk2(float a, float b) {
    return (unsigned)cvt_bf16(a) | ((unsigned)cvt_bf16(b) << 16);
}

typedef __attribute__((ext_vector_type(8))) short bf16x8;
typedef __attribute__((ext_vector_type(4))) float f32x4;

// ------------- fold weights into Bt[320][256] bf16 (B^T layout: Bt[n][k]) -------------
__global__ __launch_bounds__(256) void k_fold(
    const float* __restrict__ Wv, const float* __restrict__ Wn,
    const float* __restrict__ nbb, const float* __restrict__ wsrc,
    const float* __restrict__ wtgt, const float* __restrict__ gw,
    unsigned short* __restrict__ Bt, float* __restrict__ bg2)
{
    int k = threadIdx.x;
    int b = blockIdx.x;
    if (b < 256) {
        Bt[b * 256 + k] = cvt_bf16(Wv[k * 256 + b]);
    } else if (b < 264) {
        int h = b - 256;
        float a_vs = 0.f, a_vt = 0.f, a_ng = 0.f;
        for (int d = 0; d < 32; ++d) {
            float w = Wv[k * 256 + h * 32 + d];
            a_vs = fmaf(w, wsrc[h * 32 + d], a_vs);
            a_vt = fmaf(w, wtgt[h * 32 + d], a_vt);
        }
        for (int j = 0; j < 256; ++j)
            a_ng = fmaf(Wn[k * 256 + j], gw[(256 + j) * 8 + h], a_ng);
        Bt[(256 + h) * 256 + k] = cvt_bf16(a_vs);
        Bt[(264 + h) * 256 + k] = cvt_bf16(a_vt);
        Bt[(272 + h) * 256 + k] = cvt_bf16(gw[k * 8 + h]);
        Bt[(280 + h) * 256 + k] = cvt_bf16(a_ng);
        if (k == 0) {
            float s = 0.f;
            for (int j = 0; j < 256; ++j) s = fmaf(nbb[j], gw[(256 + j) * 8 + h], s);
            bg2[h] = s;
        }
    } else {
        int n0 = 288 + (b - 264) * 4;
        for (int i = 0; i < 4; ++i) Bt[(n0 + i) * 256 + k] = 0;
    }
}

// ------------- MFMA GEMM: [20000x256] @ Bt^T -> value(fp16) + vs/vt/g1/g2 -------------
__global__ __launch_bounds__(256) void k_mfma(
    const float* __restrict__ inp, const unsigned short* __restrict__ Bt,
    const float* __restrict__ bg2, __half* __restrict__ valh,
    float* __restrict__ vs, float* __restrict__ vt,
    float* __restrict__ g1, float* __restrict__ g2)
{
    int tid = threadIdx.x;
    int wave = tid >> 6, lane = tid & 63;
    int quad = lane >> 4, l16 = lane & 15;
    int row0 = blockIdx.x * 16;
    const float* arow = inp + (size_t)(row0 + l16) * 256;
    bf16x8 afr[8];
#pragma unroll
    for (int kk = 0; kk < 8; ++kk) {
        float4 f0 = *(const float4*)(arow + kk * 32 + quad * 8);
        float4 f1 = *(const float4*)(arow + kk * 32 + quad * 8 + 4);
        union { unsigned u[4]; bf16x8 v; } cv;
        cv.u[0] = pk2(f0.x, f0.y); cv.u[1] = pk2(f0.z, f0.w);
        cv.u[2] = pk2(f1.x, f1.y); cv.u[3] = pk2(f1.z, f1.w);
        afr[kk] = cv.v;
    }
    f32x4 acc[5] = {};
    const unsigned short* bbase = Bt + (size_t)(wave * 80 + l16) * 256 + quad * 8;
#pragma unroll
    for (int kk = 0; kk < 8; ++kk) {
#pragma unroll
        for (int t = 0; t < 5; ++t) {
            bf16x8 bf = *(const bf16x8*)(bbase + t * 16 * 256 + kk * 32);
            acc[t] = __builtin_amdgcn_mfma_f32_16x16x32_bf16(afr[kk], bf, acc[t], 0, 0, 0);
        }
    }
#pragma unroll
    for (int t = 0; t < 5; ++t) {
        int n = wave * 80 + t * 16 + l16;
#pragma unroll
        for (int r = 0; r < 4; ++r) {
            int row = row0 + quad * 4 + r;
            float v = acc[t][r];
            if (n < 256) {
                valh[(size_t)row * 256 + n] = __float2half(v);
            } else if (n < 288) {
                int c2 = n - 256, which = c2 >> 3, h = c2 & 7;
                if (which == 3) v += bg2[h];
                float* dst = (which == 0) ? vs : (which == 1) ? vt : (which == 2) ? g1 : g2;
                dst[(size_t)row * 8 + h] = v;
            }
        }
    }
}

// ------------- relation score tables -------------
__global__ void k_rel(const float* __restrict__ Wrel, const float* __restrict__ wrel,
                      const float* __restrict__ deprel_emb, const float* __restrict__ deparc_emb,
                      float* __restrict__ SA, float* __restrict__ SB)
{
    __shared__ float wr2[128 * 8];
    int t = threadIdx.x;
    for (int i = t; i < 1024; i += 256) {
        int k = i >> 3, h = i & 7;
        float acc = 0.f;
        for (int r = 0; r < 16; ++r)
            acc += Wrel[k * 128 + h * 16 + r] * wrel[h * 16 + r];
        wr2[k * 8 + h] = acc;
    }
    __syncthreads();
    for (int i = t; i < 50 * 8; i += 256) {
        int d = i >> 3, h = i & 7;
        float acc = 0.f;
        for (int k = 0; k < 64; ++k) acc += deprel_emb[d * 64 + k] * wr2[k * 8 + h];
        SA[i] = acc;
    }
    for (int i = t; i < 4 * 8; i += 256) {
        int d = i >> 3, h = i & 7;
        float acc = 0.f;
        for (int k = 0; k < 64; ++k) acc += deparc_emb[d * 64 + k] * wr2[(64 + k) * 8 + h];
        SB[i] = acc;
    }
}

// ------------- count: grid (8 slices, 80 ranges); exclusive per-(node,slice) counts -------------
__global__ __launch_bounds__(256) void k_count2(const int* __restrict__ tgt,
                                                int* __restrict__ cnts)
{
    __shared__ int cnt[250];
    int tid = threadIdx.x;
    int slice = blockIdx.x;
    int lo = blockIdx.y * 250;
    if (tid < 250) cnt[tid] = 0;
    __syncthreads();
    const int4* t4 = (const int4*)tgt;
    int i0 = slice * 5000;
#pragma unroll 4
    for (int i = tid; i < 5000; i += 256) {
        int4 v = t4[i0 + i];
        unsigned a = (unsigned)(v.x - lo); if (a < 250u) atomicAdd(&cnt[a], 1);
        unsigned b = (unsigned)(v.y - lo); if (b < 250u) atomicAdd(&cnt[b], 1);
        unsigned c = (unsigned)(v.z - lo); if (c < 250u) atomicAdd(&cnt[c], 1);
        unsigned d = (unsigned)(v.w - lo); if (d < 250u) atomicAdd(&cnt[d], 1);
    }
    __syncthreads();
    if (tid < 250) cnts[(lo + tid) * 8 + slice] = cnt[tid];
}

// ------------- deg[n] = sum over 8 slices -------------
__global__ __launch_bounds__(256) void k_sumdeg(const int* __restrict__ cnts,
                                                int* __restrict__ deg)
{
    int n = blockIdx.x * 256 + threadIdx.x;
    if (n < N_NODES) {
        const int4* c4 = (const int4*)(cnts + n * 8);
        int4 a = c4[0], b = c4[1];
        deg[n] = a.x + a.y + a.z + a.w + b.x + b.y + b.z + b.w;
    }
}

// ------------- prefix scan -------------
__global__ __launch_bounds__(1024) void k_scan(const int* __restrict__ deg,
                                               int* __restrict__ rowptr, int n)
{
    __shared__ int wbase[16];
    __shared__ int carryS;
    int t = threadIdx.x, lane = t & 63, w = t >> 6;
    if (t == 0) carryS = 0;
    __syncthreads();
    for (int base = 0; base < n; base += 1024) {
        int i = base + t;
        int v = (i < n) ? deg[i] : 0;
        int s = v;
#pragma unroll
        for (int off = 1; off < 64; off <<= 1) {
            int x = __shfl_up(s, off, 64);
            if (lane >= off) s += x;
        }
        if (lane == 63) wbase[w] = s;
        __syncthreads();
        if (t < 16) {
            int x = wbase[t];
            int ss = x;
#pragma unroll
            for (int off = 1; off < 16; off <<= 1) {
                int y = __shfl_up(ss, off, 16);
                if ((t & 15) >= off) ss += y;
            }
            wbase[t] = ss - x;
        }
        __syncthreads();
        int c = carryS;
        int excl = c + wbase[w] + s - v;
        if (i < n) rowptr[i] = excl;
        __syncthreads();
        if (t == 1023) carryS = excl + v;
        __syncthreads();
    }
    if (t == 0) rowptr[n] = carryS;
}

// ------------- fill: grid (8 slices, 80 ranges); cursors from slice prefix -------------
__global__ __launch_bounds__(256) void k_fill2(const int* __restrict__ tgt,
                                               const int* __restrict__ rowptr,
                                               const int* __restrict__ cnts,
                                               int* __restrict__ eidx)
{
    __shared__ int cur[250];
    int tid = threadIdx.x;
    int slice = blockIdx.x;
    int lo = blockIdx.y * 250;
    if (tid < 250) {
        int base = rowptr[lo + tid];
        const int* c = cnts + (size_t)(lo + tid) * 8;
        for (int s = 0; s < slice; ++s) base += c[s];
        cur[tid] = base;
    }
    __syncthreads();
    const int4* t4 = (const int4*)tgt;
    int i0 = slice * 5000;
    for (int i = tid; i < 5000; i += 256) {
        int4 v = t4[i0 + i];
        int e = (i0 + i) * 4;
        unsigned a = (unsigned)(v.x - lo); if (a < 250u) { int p = atomicAdd(&cur[a], 1); eidx[p] = e; }
        unsigned b = (unsigned)(v.y - lo); if (b < 250u) { int p = atomicAdd(&cur[b], 1); eidx[p] = e + 1; }
        unsigned c = (unsigned)(v.z - lo); if (c < 250u) { int p = atomicAdd(&cur[c], 1); eidx[p] = e + 2; }
        unsigned d = (unsigned)(v.w - lo); if (d < 250u) { int p = atomicAdd(&cur[d], 1); eidx[p] = e + 3; }
    }
}

// ------------- per-node aggregation, fp16 value rows, depth-4 prefetch -------------
__global__ __launch_bounds__(256) void k_agg(
    const __half* __restrict__ valh, const float* __restrict__ vs,
    const float* __restrict__ vt, const float* __restrict__ SA,
    const float* __restrict__ SB, const float* __restrict__ g2,
    const float* __restrict__ g1,
    const int* __restrict__ rowptr, const int* __restrict__ eidx,
    const int* __restrict__ srcArr, const int* __restrict__ deprel,
    const int* __restrict__ deparc,
    const float* __restrict__ Wp, const float* __restrict__ Pb,
    const float* __restrict__ gate_b, const float* __restrict__ final_bias,
    float* __restrict__ out)
{
    __shared__ float cat[4][548];
    __shared__ float gate_lds[4][8];
    int tid = threadIdx.x, wv = tid >> 6, l = tid & 63;
    int n = blockIdx.x * 4 + wv;
    int beg = rowptr[n], end = rowptr[n + 1];
    int deg = end - beg;
    int h8 = l >> 3;
    int q = l & 7;
    float vtq = vt[(size_t)n * 8 + q];

    float acc = 0.f;
    float4 av = make_float4(0, 0, 0, 0), ar = make_float4(0, 0, 0, 0);

    for (int base = beg; base < end; base += 64) {
        int cnt = min(64, end - base);
        int epre = 0, spre = 0, drpre = 0, dapre = 0;
        if (l < cnt) {
            epre = eidx[base + l];
            spre = srcArr[epre];
            drpre = deprel[epre];
            dapre = deparc[epre];
        }
        float rawb[4];
        uint2 vvb[4];
        auto fetch = [&](int jj, float& rawo, uint2& vvo) {
            int s1 = __shfl(spre, jj, 64);
            int dr1 = __shfl(drpre, jj, 64);
            int da1 = __shfl(dapre, jj, 64);
            float r = 0.f;
            if (l < 8)       r = vs[(size_t)s1 * 8 + q];
            else if (l < 16) r = SA[dr1 * 8 + q];
            else if (l < 24) r = g2[(size_t)s1 * 8 + q];
            else if (l < 32) r = SB[da1 * 8 + q];
            rawo = r;
            vvo = *(const uint2*)(valh + (size_t)s1 * 256 + l * 4);
        };
#pragma unroll
        for (int p = 0; p < 4; ++p) {
            int jj = (p < cnt) ? p : (cnt - 1);
            fetch(jj, rawb[p], vvb[p]);
        }
#pragma unroll 4
        for (int j = 0; j < cnt; ++j) {
            float rawc = rawb[0];
            uint2 vc = vvb[0];
            rawb[0] = rawb[1]; vvb[0] = vvb[1];
            rawb[1] = rawb[2]; vvb[1] = vvb[2];
            rawb[2] = rawb[3]; vvb[2] = vvb[3];
            int jn = j + 4;
            if (jn < cnt) fetch(jn, rawb[3], vvb[3]);

            float sb = __shfl(rawc, 24 + q, 64);
            float bvv = (l < 8) ? (rawc + vtq) : (rawc + sb + vtq);
            float tmp = (l < 16) ? exp2f(leaky(bvv) * LOG2E) : rawc;
            if (l < 24) acc += tmp;
            float wV = __shfl(tmp, h8, 64);
            float wR = __shfl(tmp, 8 + h8, 64);
            float2 f0 = __half22float2(*(__half2*)&vc.x);
            float2 f1 = __half22float2(*(__half2*)&vc.y);
            av.x = fmaf(f0.x, wV, av.x); av.y = fmaf(f0.y, wV, av.y);
            av.z = fmaf(f1.x, wV, av.z); av.w = fmaf(f1.y, wV, av.w);
            ar.x = fmaf(f0.x, wR, ar.x); ar.y = fmaf(f0.y, wR, ar.y);
            ar.z = fmaf(f1.x, wR, ar.z); ar.w = fmaf(f1.y, wR, ar.w);
        }
    }
    float dv = __shfl(acc, h8, 64) + EPSV;
    float drn = __shfl(acc, 8 + h8, 64) + EPSV;
    float rdv = 1.f / dv, rdr = 1.f / drn;
    av.x *= rdv; av.y *= rdv; av.z *= rdv; av.w *= rdv;
    ar.x *= rdr; ar.y *= rdr; ar.z *= rdr; ar.w *= rdr;

    float* cp = &cat[wv][h8 * 68 + q * 4];
    *(float4*)cp = av;
    *(float4*)(cp + 32) = ar;

    float dscale = 1.f / (float)(deg > 1 ? deg : 1);
    float gs = __shfl(acc, 16 + q, 64);
    if (l < 8) {
        float gl = g1[(size_t)n * 8 + l] + gs * dscale + gate_b[l];
        gate_lds[wv][l] = 1.f / (1.f + exp2f(-gl * LOG2E));
    }
    __syncthreads();

    // epilogue: thread -> (node nd, output group oi); 4 nodes share each Wp read
    int nd = tid & 3, oi = tid >> 2;
    int h = oi >> 3, qq = oi & 7;
    float4 ho = *(const float4*)(Pb + oi * 4);
    const float* crow = &cat[nd][h * 68];
    const float* wrow = Wp + (size_t)h * 2048 + qq * 4;
#pragma unroll 4
    for (int d = 0; d < 64; ++d) {
        float c = crow[d];
        float4 w4 = *(const float4*)(wrow + d * 32);
        ho.x = fmaf(c, w4.x, ho.x); ho.y = fmaf(c, w4.y, ho.y);
        ho.z = fmaf(c, w4.z, ho.z); ho.w = fmaf(c, w4.w, ho.w);
    }
    float g = gate_lds[nd][h];
    float4 fb = *(const float4*)(final_bias + oi * 4);
    float4 o;
    o.x = fmaf(ho.x, g, fb.x); o.y = fmaf(ho.y, g, fb.y);
    o.z = fmaf(ho.z, g, fb.z); o.w = fmaf(ho.w, g, fb.w);
    *(float4*)(out + (size_t)(blockIdx.x * 4 + nd) * 256 + oi * 4) = o;
}

extern "C" void kernel_launch(void* const* d_in, const int* in_sizes, int n_in,
                              void* d_out, int out_size, void* d_ws, size_t ws_size,
                              hipStream_t stream) {
    const float* inp         = (const float*)d_in[0];
    const float* W_value     = (const float*)d_in[2];
    const float* W_relation  = (const float*)d_in[3];
    const float* deprel_emb  = (const float*)d_in[4];
    const float* deparc_emb  = (const float*)d_in[5];
    const float* w_src       = (const float*)d_in[6];
    const float* w_tgt       = (const float*)d_in[7];
    const float* w_rel       = (const float*)d_in[8];
    const float* fpw         = (const float*)d_in[9];
    const float* fpb         = (const float*)d_in[10];
    const float* neighbor_w  = (const float*)d_in[11];
    const float* neighbor_b  = (const float*)d_in[12];
    const float* gate_w      = (const float*)d_in[13];
    const float* gate_b      = (const float*)d_in[14];
    const float* final_bias  = (const float*)d_in[15];
    const int*   edge_index  = (const int*)d_in[16];
    const int*   deprel_edge = (const int*)d_in[17];
    const int*   deparc_edge = (const int*)d_in[18];
    const int* srcArr = edge_index;
    const int* tgtArr = edge_index + N_EDGES;
    float* out = (float*)d_out;

    // workspace carve
    __half* valh = (__half*)d_ws;                                 // 5,120,000 halves
    unsigned short* Bt = (unsigned short*)(valh + 5120000);       // 81,920
    float* bg2 = (float*)(Bt + 81920);                            // 8
    float* vs = bg2 + 8;
    float* vt = vs + 160000;
    float* g1 = vt + 160000;
    float* g2 = g1 + 160000;
    float* SA = g2 + 160000;
    float* SB = SA + 400;
    int* cnts = (int*)(SB + 32);                                  // 160,000
    int* deg    = cnts + 160000;
    int* rowptr = deg + N_NODES;
    int* eidx   = rowptr + (N_NODES + 1);

    k_fold<<<272, 256, 0, stream>>>(W_value, neighbor_w, neighbor_b,
                                    w_src, w_tgt, gate_w, Bt, bg2);
    k_rel<<<1, 256, 0, stream>>>(W_relation, w_rel, deprel_emb, deparc_emb, SA, SB);
    k_mfma<<<N_NODES / 16, 256, 0, stream>>>(inp, Bt, bg2, valh, vs, vt, g1, g2);
    k_count2<<<dim3(8, 80), 256, 0, stream>>>(tgtArr, cnts);
    k_sumdeg<<<(N_NODES + 255) / 256, 256, 0, stream>>>(cnts, deg);
    k_scan<<<1, 1024, 0, stream>>>(deg, rowptr, N_NODES);
    k_fill2<<<dim3(8, 80), 256, 0, stream>>>(tgtArr, rowptr, cnts, eidx);
    k_agg<<<N_NODES / 4, 256, 0, stream>>>(valh, vs, vt, SA, SB, g2, g1,
                                           rowptr, eidx, srcArr,
                                           deprel_edge, deparc_edge,
                                           fpw, fpb, gate_b, final_bias, out);
}

// Round 6
// 272.672 us; speedup vs baseline: 2.7570x; 1.0185x over previous
//
#include <hip/hip_runtime.h>
#include <hip/hip_fp16.h>
#include <math.h>

#define N_NODES 20000
#define N_EDGES 160000
#define EPSV 1e-12f
#define SLOPE 0.2f
#define LOG2E 1.4426950408889634f

__device__ __forceinline__ float leaky(float x) { return x >= 0.f ? x : SLOPE * x; }

__device__ __forceinline__ unsigned short cvt_bf16(float f) {
    unsigned u = __float_as_uint(f);
    u = (u + 0x7FFFu + ((u >> 16) & 1u)) >> 16;
    return (unsigned short)u;
}
__device__ __forceinline__ unsigned pk2(float a, float b) {
    return (unsigned)cvt_bf16(a) | ((unsigned)cvt_bf16(b) << 16);
}

typedef __attribute__((ext_vector_type(8))) short bf16x8;
typedef __attribute__((ext_vector_type(4))) float f32x4;

// ------------- fold weights into Bt[320][256] bf16 (B^T layout: Bt[n][k]) -------------
__global__ __launch_bounds__(256) void k_fold(
    const float* __restrict__ Wv, const float* __restrict__ Wn,
    const float* __restrict__ nbb, const float* __restrict__ wsrc,
    const float* __restrict__ wtgt, const float* __restrict__ gw,
    unsigned short* __restrict__ Bt, float* __restrict__ bg2)
{
    int k = threadIdx.x;
    int b = blockIdx.x;
    if (b < 256) {
        Bt[b * 256 + k] = cvt_bf16(Wv[k * 256 + b]);
    } else if (b < 264) {
        int h = b - 256;
        float a_vs = 0.f, a_vt = 0.f, a_ng = 0.f;
        for (int d = 0; d < 32; ++d) {
            float w = Wv[k * 256 + h * 32 + d];
            a_vs = fmaf(w, wsrc[h * 32 + d], a_vs);
            a_vt = fmaf(w, wtgt[h * 32 + d], a_vt);
        }
        for (int j = 0; j < 256; ++j)
            a_ng = fmaf(Wn[k * 256 + j], gw[(256 + j) * 8 + h], a_ng);
        Bt[(256 + h) * 256 + k] = cvt_bf16(a_vs);
        Bt[(264 + h) * 256 + k] = cvt_bf16(a_vt);
        Bt[(272 + h) * 256 + k] = cvt_bf16(gw[k * 8 + h]);
        Bt[(280 + h) * 256 + k] = cvt_bf16(a_ng);
        if (k == 0) {
            float s = 0.f;
            for (int j = 0; j < 256; ++j) s = fmaf(nbb[j], gw[(256 + j) * 8 + h], s);
            bg2[h] = s;
        }
    } else {
        int n0 = 288 + (b - 264) * 4;
        for (int i = 0; i < 4; ++i) Bt[(n0 + i) * 256 + k] = 0;
    }
}

// ------------- MFMA GEMM: [20000x256] @ Bt^T -> value(fp16) + vs/vt/g1/g2 -------------
__global__ __launch_bounds__(256) void k_mfma(
    const float* __restrict__ inp, const unsigned short* __restrict__ Bt,
    const float* __restrict__ bg2, __half* __restrict__ valh,
    float* __restrict__ vs, float* __restrict__ vt,
    float* __restrict__ g1, float* __restrict__ g2)
{
    int tid = threadIdx.x;
    int wave = tid >> 6, lane = tid & 63;
    int quad = lane >> 4, l16 = lane & 15;
    int row0 = blockIdx.x * 16;
    const float* arow = inp + (size_t)(row0 + l16) * 256;
    bf16x8 afr[8];
#pragma unroll
    for (int kk = 0; kk < 8; ++kk) {
        float4 f0 = *(const float4*)(arow + kk * 32 + quad * 8);
        float4 f1 = *(const float4*)(arow + kk * 32 + quad * 8 + 4);
        union { unsigned u[4]; bf16x8 v; } cv;
        cv.u[0] = pk2(f0.x, f0.y); cv.u[1] = pk2(f0.z, f0.w);
        cv.u[2] = pk2(f1.x, f1.y); cv.u[3] = pk2(f1.z, f1.w);
        afr[kk] = cv.v;
    }
    f32x4 acc[5] = {};
    const unsigned short* bbase = Bt + (size_t)(wave * 80 + l16) * 256 + quad * 8;
#pragma unroll
    for (int kk = 0; kk < 8; ++kk) {
#pragma unroll
        for (int t = 0; t < 5; ++t) {
            bf16x8 bf = *(const bf16x8*)(bbase + t * 16 * 256 + kk * 32);
            acc[t] = __builtin_amdgcn_mfma_f32_16x16x32_bf16(afr[kk], bf, acc[t], 0, 0, 0);
        }
    }
#pragma unroll
    for (int t = 0; t < 5; ++t) {
        int n = wave * 80 + t * 16 + l16;
#pragma unroll
        for (int r = 0; r < 4; ++r) {
            int row = row0 + quad * 4 + r;
            float v = acc[t][r];
            if (n < 256) {
                valh[(size_t)row * 256 + n] = __float2half(v);
            } else if (n < 288) {
                int c2 = n - 256, which = c2 >> 3, h = c2 & 7;
                if (which == 3) v += bg2[h];
                float* dst = (which == 0) ? vs : (which == 1) ? vt : (which == 2) ? g1 : g2;
                dst[(size_t)row * 8 + h] = v;
            }
        }
    }
}

// ------------- relation score tables -------------
__global__ void k_rel(const float* __restrict__ Wrel, const float* __restrict__ wrel,
                      const float* __restrict__ deprel_emb, const float* __restrict__ deparc_emb,
                      float* __restrict__ SA, float* __restrict__ SB)
{
    __shared__ float wr2[128 * 8];
    int t = threadIdx.x;
    for (int i = t; i < 1024; i += 256) {
        int k = i >> 3, h = i & 7;
        float acc = 0.f;
        for (int r = 0; r < 16; ++r)
            acc += Wrel[k * 128 + h * 16 + r] * wrel[h * 16 + r];
        wr2[k * 8 + h] = acc;
    }
    __syncthreads();
    for (int i = t; i < 50 * 8; i += 256) {
        int d = i >> 3, h = i & 7;
        float acc = 0.f;
        for (int k = 0; k < 64; ++k) acc += deprel_emb[d * 64 + k] * wr2[k * 8 + h];
        SA[i] = acc;
    }
    for (int i = t; i < 4 * 8; i += 256) {
        int d = i >> 3, h = i & 7;
        float acc = 0.f;
        for (int k = 0; k < 64; ++k) acc += deparc_emb[d * 64 + k] * wr2[(64 + k) * 8 + h];
        SB[i] = acc;
    }
}

// ------------- edge-parallel: pw[e][24] = {exp(s_v[h]), exp(s_r[h]), g2[src][h]} -------------
__global__ __launch_bounds__(256) void k_escore(
    const float* __restrict__ vs, const float* __restrict__ vt,
    const float* __restrict__ SA, const float* __restrict__ SB,
    const float* __restrict__ g2,
    const int* __restrict__ src, const int* __restrict__ tgt,
    const int* __restrict__ deprel, const int* __restrict__ deparc,
    float* __restrict__ pw)
{
    int e = blockIdx.x * 256 + threadIdx.x;
    int s = src[e], t = tgt[e], dr = deprel[e], da = deparc[e];
    const float4* vs4 = (const float4*)(vs + (size_t)s * 8);
    const float4* vt4 = (const float4*)(vt + (size_t)t * 8);
    const float4* SA4 = (const float4*)(SA + dr * 8);
    const float4* SB4 = (const float4*)(SB + da * 8);
    const float4* g24 = (const float4*)(g2 + (size_t)s * 8);
    float4 a0 = vs4[0], a1 = vs4[1];
    float4 b0 = vt4[0], b1 = vt4[1];
    float4 ra0 = SA4[0], ra1 = SA4[1];
    float4 rb0 = SB4[0], rb1 = SB4[1];
    float4 gg0 = g24[0], gg1 = g24[1];
    float av[8] = {a0.x, a0.y, a0.z, a0.w, a1.x, a1.y, a1.z, a1.w};
    float bv[8] = {b0.x, b0.y, b0.z, b0.w, b1.x, b1.y, b1.z, b1.w};
    float rv[8] = {ra0.x + rb0.x, ra0.y + rb0.y, ra0.z + rb0.z, ra0.w + rb0.w,
                   ra1.x + rb1.x, ra1.y + rb1.y, ra1.z + rb1.z, ra1.w + rb1.w};
    float ev[8], er[8];
#pragma unroll
    for (int h = 0; h < 8; ++h) {
        ev[h] = exp2f(leaky(av[h] + bv[h]) * LOG2E);
        er[h] = exp2f(leaky(rv[h] + bv[h]) * LOG2E);
    }
    float4* o = (float4*)(pw + (size_t)e * 24);
    o[0] = make_float4(ev[0], ev[1], ev[2], ev[3]);
    o[1] = make_float4(ev[4], ev[5], ev[6], ev[7]);
    o[2] = make_float4(er[0], er[1], er[2], er[3]);
    o[3] = make_float4(er[4], er[5], er[6], er[7]);
    o[4] = gg0;
    o[5] = gg1;
}

// ------------- count: grid (8 slices, 80 ranges) -------------
__global__ __launch_bounds__(256) void k_count2(const int* __restrict__ tgt,
                                                int* __restrict__ cnts)
{
    __shared__ int cnt[250];
    int tid = threadIdx.x;
    int slice = blockIdx.x;
    int lo = blockIdx.y * 250;
    if (tid < 250) cnt[tid] = 0;
    __syncthreads();
    const int4* t4 = (const int4*)tgt;
    int i0 = slice * 5000;
#pragma unroll 4
    for (int i = tid; i < 5000; i += 256) {
        int4 v = t4[i0 + i];
        unsigned a = (unsigned)(v.x - lo); if (a < 250u) atomicAdd(&cnt[a], 1);
        unsigned b = (unsigned)(v.y - lo); if (b < 250u) atomicAdd(&cnt[b], 1);
        unsigned c = (unsigned)(v.z - lo); if (c < 250u) atomicAdd(&cnt[c], 1);
        unsigned d = (unsigned)(v.w - lo); if (d < 250u) atomicAdd(&cnt[d], 1);
    }
    __syncthreads();
    if (tid < 250) cnts[(lo + tid) * 8 + slice] = cnt[tid];
}

// ------------- deg[n] = sum over 8 slices -------------
__global__ __launch_bounds__(256) void k_sumdeg(const int* __restrict__ cnts,
                                                int* __restrict__ deg)
{
    int n = blockIdx.x * 256 + threadIdx.x;
    if (n < N_NODES) {
        const int4* c4 = (const int4*)(cnts + n * 8);
        int4 a = c4[0], b = c4[1];
        deg[n] = a.x + a.y + a.z + a.w + b.x + b.y + b.z + b.w;
    }
}

// ------------- prefix scan -------------
__global__ __launch_bounds__(1024) void k_scan(const int* __restrict__ deg,
                                               int* __restrict__ rowptr, int n)
{
    __shared__ int wbase[16];
    __shared__ int carryS;
    int t = threadIdx.x, lane = t & 63, w = t >> 6;
    if (t == 0) carryS = 0;
    __syncthreads();
    for (int base = 0; base < n; base += 1024) {
        int i = base + t;
        int v = (i < n) ? deg[i] : 0;
        int s = v;
#pragma unroll
        for (int off = 1; off < 64; off <<= 1) {
            int x = __shfl_up(s, off, 64);
            if (lane >= off) s += x;
        }
        if (lane == 63) wbase[w] = s;
        __syncthreads();
        if (t < 16) {
            int x = wbase[t];
            int ss = x;
#pragma unroll
            for (int off = 1; off < 16; off <<= 1) {
                int y = __shfl_up(ss, off, 16);
                if ((t & 15) >= off) ss += y;
            }
            wbase[t] = ss - x;
        }
        __syncthreads();
        int c = carryS;
        int excl = c + wbase[w] + s - v;
        if (i < n) rowptr[i] = excl;
        __syncthreads();
        if (t == 1023) carryS = excl + v;
        __syncthreads();
    }
    if (t == 0) rowptr[n] = carryS;
}

// ------------- fill: grid (8 slices, 80 ranges) -------------
__global__ __launch_bounds__(256) void k_fill2(const int* __restrict__ tgt,
                                               const int* __restrict__ rowptr,
                                               const int* __restrict__ cnts,
                                               int* __restrict__ eidx)
{
    __shared__ int cur[250];
    int tid = threadIdx.x;
    int slice = blockIdx.x;
    int lo = blockIdx.y * 250;
    if (tid < 250) {
        int base = rowptr[lo + tid];
        const int* c = cnts + (size_t)(lo + tid) * 8;
        for (int s = 0; s < slice; ++s) base += c[s];
        cur[tid] = base;
    }
    __syncthreads();
    const int4* t4 = (const int4*)tgt;
    int i0 = slice * 5000;
    for (int i = tid; i < 5000; i += 256) {
        int4 v = t4[i0 + i];
        int e = (i0 + i) * 4;
        unsigned a = (unsigned)(v.x - lo); if (a < 250u) { int p = atomicAdd(&cur[a], 1); eidx[p] = e; }
        unsigned b = (unsigned)(v.y - lo); if (b < 250u) { int p = atomicAdd(&cur[b], 1); eidx[p] = e + 1; }
        unsigned c = (unsigned)(v.z - lo); if (c < 250u) { int p = atomicAdd(&cur[c], 1); eidx[p] = e + 2; }
        unsigned d = (unsigned)(v.w - lo); if (d < 250u) { int p = atomicAdd(&cur[d], 1); eidx[p] = e + 3; }
    }
}

// ------------- per-node aggregation: precomputed pw, fp16 rows, depth-1 prefetch -------------
__global__ __launch_bounds__(256) void k_agg(
    const __half* __restrict__ valh, const float* __restrict__ pw,
    const float* __restrict__ g1,
    const int* __restrict__ rowptr, const int* __restrict__ eidx,
    const int* __restrict__ srcArr,
    const float* __restrict__ Wp, const float* __restrict__ Pb,
    const float* __restrict__ gate_b, const float* __restrict__ final_bias,
    float* __restrict__ out)
{
    __shared__ float cat[4][548];
    __shared__ float gate_lds[4][8];
    int tid = threadIdx.x, wv = tid >> 6, l = tid & 63;
    int n = blockIdx.x * 4 + wv;
    int beg = rowptr[n], end = rowptr[n + 1];
    int deg = end - beg;
    int h8 = l >> 3;
    int q = l & 7;

    float acc = 0.f;
    float4 av = make_float4(0, 0, 0, 0), ar = make_float4(0, 0, 0, 0);

    for (int base = beg; base < end; base += 64) {
        int cnt = min(64, end - base);
        int epre = 0, spre = 0;
        if (l < cnt) {
            epre = eidx[base + l];
            spre = srcArr[epre];
        }
        int e0 = __shfl(epre, 0, 64);
        int s0 = __shfl(spre, 0, 64);
        float pwc = (l < 24) ? pw[(size_t)e0 * 24 + l] : 0.f;
        uint2 vvc = *(const uint2*)(valh + (size_t)s0 * 256 + l * 4);
        for (int j = 0; j < cnt; ++j) {
            float pwn = pwc;
            uint2 vvn = vvc;
            if (j + 1 < cnt) {
                int e1 = __shfl(epre, j + 1, 64);
                int s1 = __shfl(spre, j + 1, 64);
                pwn = (l < 24) ? pw[(size_t)e1 * 24 + l] : 0.f;
                vvn = *(const uint2*)(valh + (size_t)s1 * 256 + l * 4);
            }
            float tmp = pwc;
            if (l < 24) acc += tmp;
            float wV = __shfl(tmp, h8, 64);
            float wR = __shfl(tmp, 8 + h8, 64);
            float2 f0 = __half22float2(*(__half2*)&vvc.x);
            float2 f1 = __half22float2(*(__half2*)&vvc.y);
            av.x = fmaf(f0.x, wV, av.x); av.y = fmaf(f0.y, wV, av.y);
            av.z = fmaf(f1.x, wV, av.z); av.w = fmaf(f1.y, wV, av.w);
            ar.x = fmaf(f0.x, wR, ar.x); ar.y = fmaf(f0.y, wR, ar.y);
            ar.z = fmaf(f1.x, wR, ar.z); ar.w = fmaf(f1.y, wR, ar.w);
            pwc = pwn; vvc = vvn;
        }
    }
    float dv = __shfl(acc, h8, 64) + EPSV;
    float drn = __shfl(acc, 8 + h8, 64) + EPSV;
    float rdv = 1.f / dv, rdr = 1.f / drn;
    av.x *= rdv; av.y *= rdv; av.z *= rdv; av.w *= rdv;
    ar.x *= rdr; ar.y *= rdr; ar.z *= rdr; ar.w *= rdr;

    float* cp = &cat[wv][h8 * 68 + q * 4];
    *(float4*)cp = av;
    *(float4*)(cp + 32) = ar;

    float dscale = 1.f / (float)(deg > 1 ? deg : 1);
    float gs = __shfl(acc, 16 + q, 64);
    if (l < 8) {
        float gl = g1[(size_t)n * 8 + l] + gs * dscale + gate_b[l];
        gate_lds[wv][l] = 1.f / (1.f + exp2f(-gl * LOG2E));
    }
    __syncthreads();

    // epilogue: thread -> (node nd, output group oi); 4 nodes share each Wp read
    int nd = tid & 3, oi = tid >> 2;
    int h = oi >> 3, qq = oi & 7;
    float4 ho = *(const float4*)(Pb + oi * 4);
    const float* crow = &cat[nd][h * 68];
    const float* wrow = Wp + (size_t)h * 2048 + qq * 4;
#pragma unroll 4
    for (int d = 0; d < 64; ++d) {
        float c = crow[d];
        float4 w4 = *(const float4*)(wrow + d * 32);
        ho.x = fmaf(c, w4.x, ho.x); ho.y = fmaf(c, w4.y, ho.y);
        ho.z = fmaf(c, w4.z, ho.z); ho.w = fmaf(c, w4.w, ho.w);
    }
    float g = gate_lds[nd][h];
    float4 fb = *(const float4*)(final_bias + oi * 4);
    float4 o;
    o.x = fmaf(ho.x, g, fb.x); o.y = fmaf(ho.y, g, fb.y);
    o.z = fmaf(ho.z, g, fb.z); o.w = fmaf(ho.w, g, fb.w);
    *(float4*)(out + (size_t)(blockIdx.x * 4 + nd) * 256 + oi * 4) = o;
}

extern "C" void kernel_launch(void* const* d_in, const int* in_sizes, int n_in,
                              void* d_out, int out_size, void* d_ws, size_t ws_size,
                              hipStream_t stream) {
    const float* inp         = (const float*)d_in[0];
    const float* W_value     = (const float*)d_in[2];
    const float* W_relation  = (const float*)d_in[3];
    const float* deprel_emb  = (const float*)d_in[4];
    const float* deparc_emb  = (const float*)d_in[5];
    const float* w_src       = (const float*)d_in[6];
    const float* w_tgt       = (const float*)d_in[7];
    const float* w_rel       = (const float*)d_in[8];
    const float* fpw         = (const float*)d_in[9];
    const float* fpb         = (const float*)d_in[10];
    const float* neighbor_w  = (const float*)d_in[11];
    const float* neighbor_b  = (const float*)d_in[12];
    const float* gate_w      = (const float*)d_in[13];
    const float* gate_b      = (const float*)d_in[14];
    const float* final_bias  = (const float*)d_in[15];
    const int*   edge_index  = (const int*)d_in[16];
    const int*   deprel_edge = (const int*)d_in[17];
    const int*   deparc_edge = (const int*)d_in[18];
    const int* srcArr = edge_index;
    const int* tgtArr = edge_index + N_EDGES;
    float* out = (float*)d_out;

    // workspace carve
    __half* valh = (__half*)d_ws;                                 // 5,120,000 halves (10.24 MB)
    unsigned short* Bt = (unsigned short*)(valh + 5120000);       // 81,920
    float* bg2 = (float*)(Bt + 81920);                            // 8
    float* vs = bg2 + 8;
    float* vt = vs + 160000;
    float* g1 = vt + 160000;
    float* g2 = g1 + 160000;
    float* SA = g2 + 160000;
    float* SB = SA + 400;
    float* pw = SB + 32;                                          // 3,840,000 (15.36 MB)
    int* cnts = (int*)(pw + (size_t)N_EDGES * 24);                // 160,000
    int* deg    = cnts + 160000;
    int* rowptr = deg + N_NODES;
    int* eidx   = rowptr + (N_NODES + 1);

    k_fold<<<272, 256, 0, stream>>>(W_value, neighbor_w, neighbor_b,
                                    w_src, w_tgt, gate_w, Bt, bg2);
    k_rel<<<1, 256, 0, stream>>>(W_relation, w_rel, deprel_emb, deparc_emb, SA, SB);
    k_mfma<<<N_NODES / 16, 256, 0, stream>>>(inp, Bt, bg2, valh, vs, vt, g1, g2);
    k_count2<<<dim3(8, 80), 256, 0, stream>>>(tgtArr, cnts);
    k_sumdeg<<<(N_NODES + 255) / 256, 256, 0, stream>>>(cnts, deg);
    k_escore<<<N_EDGES / 256, 256, 0, stream>>>(vs, vt, SA, SB, g2, srcArr, tgtArr,
                                                deprel_edge, deparc_edge, pw);
    k_scan<<<1, 1024, 0, stream>>>(deg, rowptr, N_NODES);
    k_fill2<<<dim3(8, 80), 256, 0, stream>>>(tgtArr, rowptr, cnts, eidx);
    k_agg<<<N_NODES / 4, 256, 0, stream>>>(valh, pw, g1, rowptr, eidx, srcArr,
                                           fpw, fpb, gate_b, final_bias, out);
}

// Round 7
// 266.183 us; speedup vs baseline: 2.8242x; 1.0244x over previous
//
#include <hip/hip_runtime.h>
#include <hip/hip_fp16.h>
#include <math.h>

#define N_NODES 20000
#define N_EDGES 160000
#define EPSV 1e-12f
#define SLOPE 0.2f
#define LOG2E 1.4426950408889634f

__device__ __forceinline__ float leaky(float x) { return x >= 0.f ? x : SLOPE * x; }

__device__ __forceinline__ unsigned short cvt_bf16(float f) {
    unsigned u = __float_as_uint(f);
    u = (u + 0x7FFFu + ((u >> 16) & 1u)) >> 16;
    return (unsigned short)u;
}
__device__ __forceinline__ unsigned pk2(float a, float b) {
    return (unsigned)cvt_bf16(a) | ((unsigned)cvt_bf16(b) << 16);
}

typedef __attribute__((ext_vector_type(8))) short bf16x8;
typedef __attribute__((ext_vector_type(4))) float f32x4;

// ------------- fused fold (blocks 0..271) + relation tables (block 272) -------------
__global__ __launch_bounds__(256) void k_foldrel(
    const float* __restrict__ Wv, const float* __restrict__ Wn,
    const float* __restrict__ nbb, const float* __restrict__ wsrc,
    const float* __restrict__ wtgt, const float* __restrict__ gw,
    unsigned short* __restrict__ Bt, float* __restrict__ bg2,
    const float* __restrict__ Wrel, const float* __restrict__ wrel,
    const float* __restrict__ deprel_emb, const float* __restrict__ deparc_emb,
    float* __restrict__ SA, float* __restrict__ SB)
{
    __shared__ float wr2[128 * 8];
    int k = threadIdx.x;
    int b = blockIdx.x;
    if (b < 256) {
        Bt[b * 256 + k] = cvt_bf16(Wv[k * 256 + b]);
    } else if (b < 264) {
        int h = b - 256;
        float a_vs = 0.f, a_vt = 0.f, a_ng = 0.f;
        for (int d = 0; d < 32; ++d) {
            float w = Wv[k * 256 + h * 32 + d];
            a_vs = fmaf(w, wsrc[h * 32 + d], a_vs);
            a_vt = fmaf(w, wtgt[h * 32 + d], a_vt);
        }
        for (int j = 0; j < 256; ++j)
            a_ng = fmaf(Wn[k * 256 + j], gw[(256 + j) * 8 + h], a_ng);
        Bt[(256 + h) * 256 + k] = cvt_bf16(a_vs);
        Bt[(264 + h) * 256 + k] = cvt_bf16(a_vt);
        Bt[(272 + h) * 256 + k] = cvt_bf16(gw[k * 8 + h]);
        Bt[(280 + h) * 256 + k] = cvt_bf16(a_ng);
        if (k == 0) {
            float s = 0.f;
            for (int j = 0; j < 256; ++j) s = fmaf(nbb[j], gw[(256 + j) * 8 + h], s);
            bg2[h] = s;
        }
    } else if (b < 272) {
        int n0 = 288 + (b - 264) * 4;
        for (int i = 0; i < 4; ++i) Bt[(n0 + i) * 256 + k] = 0;
    } else {
        // relation tables
        int t = k;
        for (int i = t; i < 1024; i += 256) {
            int kk = i >> 3, h = i & 7;
            float acc = 0.f;
            for (int r = 0; r < 16; ++r)
                acc += Wrel[kk * 128 + h * 16 + r] * wrel[h * 16 + r];
            wr2[kk * 8 + h] = acc;
        }
        __syncthreads();
        for (int i = t; i < 50 * 8; i += 256) {
            int d = i >> 3, h = i & 7;
            float acc = 0.f;
            for (int kk = 0; kk < 64; ++kk) acc += deprel_emb[d * 64 + kk] * wr2[kk * 8 + h];
            SA[i] = acc;
        }
        for (int i = t; i < 4 * 8; i += 256) {
            int d = i >> 3, h = i & 7;
            float acc = 0.f;
            for (int kk = 0; kk < 64; ++kk) acc += deparc_emb[d * 64 + kk] * wr2[(64 + kk) * 8 + h];
            SB[i] = acc;
        }
    }
}

// ------------- MFMA GEMM: [20000x256] @ Bt^T -> value(fp16) + vs/vt/g1/g2 -------------
__global__ __launch_bounds__(256) void k_mfma(
    const float* __restrict__ inp, const unsigned short* __restrict__ Bt,
    const float* __restrict__ bg2, __half* __restrict__ valh,
    float* __restrict__ vs, float* __restrict__ vt,
    float* __restrict__ g1, float* __restrict__ g2)
{
    int tid = threadIdx.x;
    int wave = tid >> 6, lane = tid & 63;
    int quad = lane >> 4, l16 = lane & 15;
    int row0 = blockIdx.x * 16;
    const float* arow = inp + (size_t)(row0 + l16) * 256;
    bf16x8 afr[8];
#pragma unroll
    for (int kk = 0; kk < 8; ++kk) {
        float4 f0 = *(const float4*)(arow + kk * 32 + quad * 8);
        float4 f1 = *(const float4*)(arow + kk * 32 + quad * 8 + 4);
        union { unsigned u[4]; bf16x8 v; } cv;
        cv.u[0] = pk2(f0.x, f0.y); cv.u[1] = pk2(f0.z, f0.w);
        cv.u[2] = pk2(f1.x, f1.y); cv.u[3] = pk2(f1.z, f1.w);
        afr[kk] = cv.v;
    }
    f32x4 acc[5] = {};
    const unsigned short* bbase = Bt + (size_t)(wave * 80 + l16) * 256 + quad * 8;
#pragma unroll
    for (int kk = 0; kk < 8; ++kk) {
#pragma unroll
        for (int t = 0; t < 5; ++t) {
            bf16x8 bf = *(const bf16x8*)(bbase + t * 16 * 256 + kk * 32);
            acc[t] = __builtin_amdgcn_mfma_f32_16x16x32_bf16(afr[kk], bf, acc[t], 0, 0, 0);
        }
    }
#pragma unroll
    for (int t = 0; t < 5; ++t) {
        int n = wave * 80 + t * 16 + l16;
#pragma unroll
        for (int r = 0; r < 4; ++r) {
            int row = row0 + quad * 4 + r;
            float v = acc[t][r];
            if (n < 256) {
                valh[(size_t)row * 256 + n] = __float2half(v);
            } else if (n < 288) {
                int c2 = n - 256, which = c2 >> 3, h = c2 & 7;
                if (which == 3) v += bg2[h];
                float* dst = (which == 0) ? vs : (which == 1) ? vt : (which == 2) ? g1 : g2;
                dst[(size_t)row * 8 + h] = v;
            }
        }
    }
}

// ------------- edge-parallel: pw[e][24] = {exp(s_v[h]), exp(s_r[h]), g2[src][h]} -------------
__global__ __launch_bounds__(256) void k_escore(
    const float* __restrict__ vs, const float* __restrict__ vt,
    const float* __restrict__ SA, const float* __restrict__ SB,
    const float* __restrict__ g2,
    const int* __restrict__ src, const int* __restrict__ tgt,
    const int* __restrict__ deprel, const int* __restrict__ deparc,
    float* __restrict__ pw)
{
    int e = blockIdx.x * 256 + threadIdx.x;
    int s = src[e], t = tgt[e], dr = deprel[e], da = deparc[e];
    const float4* vs4 = (const float4*)(vs + (size_t)s * 8);
    const float4* vt4 = (const float4*)(vt + (size_t)t * 8);
    const float4* SA4 = (const float4*)(SA + dr * 8);
    const float4* SB4 = (const float4*)(SB + da * 8);
    const float4* g24 = (const float4*)(g2 + (size_t)s * 8);
    float4 a0 = vs4[0], a1 = vs4[1];
    float4 b0 = vt4[0], b1 = vt4[1];
    float4 ra0 = SA4[0], ra1 = SA4[1];
    float4 rb0 = SB4[0], rb1 = SB4[1];
    float4 gg0 = g24[0], gg1 = g24[1];
    float av[8] = {a0.x, a0.y, a0.z, a0.w, a1.x, a1.y, a1.z, a1.w};
    float bv[8] = {b0.x, b0.y, b0.z, b0.w, b1.x, b1.y, b1.z, b1.w};
    float rv[8] = {ra0.x + rb0.x, ra0.y + rb0.y, ra0.z + rb0.z, ra0.w + rb0.w,
                   ra1.x + rb1.x, ra1.y + rb1.y, ra1.z + rb1.z, ra1.w + rb1.w};
    float ev[8], er[8];
#pragma unroll
    for (int h = 0; h < 8; ++h) {
        ev[h] = exp2f(leaky(av[h] + bv[h]) * LOG2E);
        er[h] = exp2f(leaky(rv[h] + bv[h]) * LOG2E);
    }
    float4* o = (float4*)(pw + (size_t)e * 24);
    o[0] = make_float4(ev[0], ev[1], ev[2], ev[3]);
    o[1] = make_float4(ev[4], ev[5], ev[6], ev[7]);
    o[2] = make_float4(er[0], er[1], er[2], er[3]);
    o[3] = make_float4(er[4], er[5], er[6], er[7]);
    o[4] = gg0;
    o[5] = gg1;
}

// ------------- count: grid (8 slices, 80 ranges) -------------
__global__ __launch_bounds__(256) void k_count2(const int* __restrict__ tgt,
                                                int* __restrict__ cnts)
{
    __shared__ int cnt[250];
    int tid = threadIdx.x;
    int slice = blockIdx.x;
    int lo = blockIdx.y * 250;
    if (tid < 250) cnt[tid] = 0;
    __syncthreads();
    const int4* t4 = (const int4*)tgt;
    int i0 = slice * 5000;
#pragma unroll 4
    for (int i = tid; i < 5000; i += 256) {
        int4 v = t4[i0 + i];
        unsigned a = (unsigned)(v.x - lo); if (a < 250u) atomicAdd(&cnt[a], 1);
        unsigned b = (unsigned)(v.y - lo); if (b < 250u) atomicAdd(&cnt[b], 1);
        unsigned c = (unsigned)(v.z - lo); if (c < 250u) atomicAdd(&cnt[c], 1);
        unsigned d = (unsigned)(v.w - lo); if (d < 250u) atomicAdd(&cnt[d], 1);
    }
    __syncthreads();
    if (tid < 250) cnts[(lo + tid) * 8 + slice] = cnt[tid];
}

// ------------- fused sumdeg + scan: single block, u16 LDS degree table -------------
__global__ __launch_bounds__(1024) void k_scan2(const int* __restrict__ cnts,
                                                int* __restrict__ rowptr)
{
    __shared__ unsigned short degl[N_NODES];   // 40 KB; max deg << 65536
    __shared__ int wsum[16];
    int t = threadIdx.x, lane = t & 63, w = t >> 6;
    // phase A: deg[n] = sum of 8 slice counts (coalesced int4 reads)
    for (int k = 0; k < 20; ++k) {
        int nn = k * 1024 + t;
        if (nn < N_NODES) {
            const int4* c4 = (const int4*)(cnts + (size_t)nn * 8);
            int4 a = c4[0], b = c4[1];
            degl[nn] = (unsigned short)(a.x + a.y + a.z + a.w + b.x + b.y + b.z + b.w);
        }
    }
    __syncthreads();
    // phase B: thread t (<1000) owns nodes t*20..t*20+19
    int s = 0;
    if (t < 1000) {
#pragma unroll 4
        for (int k = 0; k < 20; ++k) s += degl[t * 20 + k];
    }
    int ps = s;
#pragma unroll
    for (int off = 1; off < 64; off <<= 1) {
        int x = __shfl_up(ps, off, 64);
        if (lane >= off) ps += x;
    }
    if (lane == 63) wsum[w] = ps;
    __syncthreads();
    if (t < 16) {
        int x = wsum[t];
        int ss = x;
#pragma unroll
        for (int off = 1; off < 16; off <<= 1) {
            int y = __shfl_up(ss, off, 16);
            if (t >= off) ss += y;
        }
        wsum[t] = ss - x;  // exclusive
    }
    __syncthreads();
    int excl = wsum[w] + ps - s;
    // phase C: write rowptr for owned nodes
    if (t < 1000) {
        int run = excl;
        for (int k = 0; k < 20; ++k) {
            rowptr[t * 20 + k] = run;
            run += degl[t * 20 + k];
        }
        if (t == 999) rowptr[N_NODES] = run;
    }
}

// ------------- fill: grid (8 slices, 80 ranges) -------------
__global__ __launch_bounds__(256) void k_fill2(const int* __restrict__ tgt,
                                               const int* __restrict__ rowptr,
                                               const int* __restrict__ cnts,
                                               int* __restrict__ eidx)
{
    __shared__ int cur[250];
    int tid = threadIdx.x;
    int slice = blockIdx.x;
    int lo = blockIdx.y * 250;
    if (tid < 250) {
        int base = rowptr[lo + tid];
        const int* c = cnts + (size_t)(lo + tid) * 8;
        for (int s = 0; s < slice; ++s) base += c[s];
        cur[tid] = base;
    }
    __syncthreads();
    const int4* t4 = (const int4*)tgt;
    int i0 = slice * 5000;
    for (int i = tid; i < 5000; i += 256) {
        int4 v = t4[i0 + i];
        int e = (i0 + i) * 4;
        unsigned a = (unsigned)(v.x - lo); if (a < 250u) { int p = atomicAdd(&cur[a], 1); eidx[p] = e; }
        unsigned b = (unsigned)(v.y - lo); if (b < 250u) { int p = atomicAdd(&cur[b], 1); eidx[p] = e + 1; }
        unsigned c = (unsigned)(v.z - lo); if (c < 250u) { int p = atomicAdd(&cur[c], 1); eidx[p] = e + 2; }
        unsigned d = (unsigned)(v.w - lo); if (d < 250u) { int p = atomicAdd(&cur[d], 1); eidx[p] = e + 3; }
    }
}

// ------------- per-node aggregation: 2 edges/wave-iter, depth-2 pair prefetch -------------
__global__ __launch_bounds__(256) void k_agg(
    const __half* __restrict__ valh, const float* __restrict__ pw,
    const float* __restrict__ g1,
    const int* __restrict__ rowptr, const int* __restrict__ eidx,
    const int* __restrict__ srcArr,
    const float* __restrict__ Wp, const float* __restrict__ Pb,
    const float* __restrict__ gate_b, const float* __restrict__ final_bias,
    float* __restrict__ out)
{
    __shared__ float cat[4][548];
    __shared__ float gate_lds[4][8];
    int tid = threadIdx.x, wv = tid >> 6, l = tid & 63;
    int half = l >> 5, l5 = l & 31;
    int n = blockIdx.x * 4 + wv;
    int beg = rowptr[n], end = rowptr[n + 1];
    int deg = end - beg;

    float acc = 0.f;
    float av[8] = {0,0,0,0,0,0,0,0}, ar[8] = {0,0,0,0,0,0,0,0};

    for (int base = beg; base < end; base += 64) {
        int cnt = min(64, end - base);
        int epre = 0, spre = 0;
        if (l < cnt) { epre = eidx[base + l]; spre = srcArr[epre]; }
        int npair = (cnt + 1) >> 1;
        float pwb[2];
        uint4 vvb[2];
        bool vb[2];
        auto fetchp = [&](int p, int slot) {
            int idx = 2 * p + half;
            bool valid = idx < cnt;
            int cidx = valid ? idx : (cnt - 1);
            int e1 = __shfl(epre, cidx, 64);
            int s1 = __shfl(spre, cidx, 64);
            pwb[slot] = (l5 < 24) ? pw[(size_t)e1 * 24 + l5] : 0.f;
            vvb[slot] = *(const uint4*)(valh + (size_t)s1 * 256 + l5 * 8);
            vb[slot] = valid;
        };
        fetchp(0, 0);
        if (npair > 1) fetchp(1, 1);
        for (int p = 0; p < npair; ++p) {
            int slot = p & 1;
            float pwc = pwb[slot];
            uint4 vc = vvb[slot];
            bool valid = vb[slot];
            if (p + 2 < npair) fetchp(p + 2, slot);
            float tmp = valid ? pwc : 0.f;
            if (l5 < 24) acc += tmp;
            int srcb = (l & 32) + (l5 >> 2);
            float wV = __shfl(tmp, srcb, 64);
            float wR = __shfl(tmp, srcb + 8, 64);
            __half2* hp = (__half2*)&vc;
#pragma unroll
            for (int k = 0; k < 4; ++k) {
                float2 f = __half22float2(hp[k]);
                av[2 * k]     = fmaf(f.x, wV, av[2 * k]);
                av[2 * k + 1] = fmaf(f.y, wV, av[2 * k + 1]);
                ar[2 * k]     = fmaf(f.x, wR, ar[2 * k]);
                ar[2 * k + 1] = fmaf(f.y, wR, ar[2 * k + 1]);
            }
        }
    }
    // merge the two half-wave partials
    acc += __shfl_xor(acc, 32, 64);
#pragma unroll
    for (int k = 0; k < 8; ++k) {
        av[k] += __shfl_xor(av[k], 32, 64);
        ar[k] += __shfl_xor(ar[k], 32, 64);
    }
    int h = l5 >> 2;
    float dv = __shfl(acc, h, 64) + EPSV;
    float drn = __shfl(acc, 8 + h, 64) + EPSV;
    float rdv = 1.f / dv, rdr = 1.f / drn;
    if (half == 0) {
        // lane l5 covers dims l5*8..+7 => head h, within-head offset (l5&3)*8
        float* cp = &cat[wv][h * 68 + (l5 & 3) * 8];
        float4 w0 = make_float4(av[0] * rdv, av[1] * rdv, av[2] * rdv, av[3] * rdv);
        float4 w1 = make_float4(av[4] * rdv, av[5] * rdv, av[6] * rdv, av[7] * rdv);
        float4 w2 = make_float4(ar[0] * rdr, ar[1] * rdr, ar[2] * rdr, ar[3] * rdr);
        float4 w3 = make_float4(ar[4] * rdr, ar[5] * rdr, ar[6] * rdr, ar[7] * rdr);
        *(float4*)cp = w0;
        *(float4*)(cp + 4) = w1;
        *(float4*)(cp + 32) = w2;
        *(float4*)(cp + 36) = w3;
    }
    float dscale = 1.f / (float)(deg > 1 ? deg : 1);
    float gs = __shfl(acc, 16 + (l & 7), 64);
    if (l < 8) {
        float gl = g1[(size_t)n * 8 + l] + gs * dscale + gate_b[l];
        gate_lds[wv][l] = 1.f / (1.f + exp2f(-gl * LOG2E));
    }
    __syncthreads();

    // epilogue: thread -> (node nd, output group oi); 4 nodes share each Wp read
    int nd = tid & 3, oi = tid >> 2;
    int hh = oi >> 3, qq = oi & 7;
    float4 ho = *(const float4*)(Pb + oi * 4);
    const float* crow = &cat[nd][hh * 68];
    const float* wrow = Wp + (size_t)hh * 2048 + qq * 4;
#pragma unroll 4
    for (int d = 0; d < 64; ++d) {
        float c = crow[d];
        float4 w4 = *(const float4*)(wrow + d * 32);
        ho.x = fmaf(c, w4.x, ho.x); ho.y = fmaf(c, w4.y, ho.y);
        ho.z = fmaf(c, w4.z, ho.z); ho.w = fmaf(c, w4.w, ho.w);
    }
    float g = gate_lds[nd][hh];
    float4 fb = *(const float4*)(final_bias + oi * 4);
    float4 o;
    o.x = fmaf(ho.x, g, fb.x); o.y = fmaf(ho.y, g, fb.y);
    o.z = fmaf(ho.z, g, fb.z); o.w = fmaf(ho.w, g, fb.w);
    *(float4*)(out + (size_t)(blockIdx.x * 4 + nd) * 256 + oi * 4) = o;
}

extern "C" void kernel_launch(void* const* d_in, const int* in_sizes, int n_in,
                              void* d_out, int out_size, void* d_ws, size_t ws_size,
                              hipStream_t stream) {
    const float* inp         = (const float*)d_in[0];
    const float* W_value     = (const float*)d_in[2];
    const float* W_relation  = (const float*)d_in[3];
    const float* deprel_emb  = (const float*)d_in[4];
    const float* deparc_emb  = (const float*)d_in[5];
    const float* w_src       = (const float*)d_in[6];
    const float* w_tgt       = (const float*)d_in[7];
    const float* w_rel       = (const float*)d_in[8];
    const float* fpw         = (const float*)d_in[9];
    const float* fpb         = (const float*)d_in[10];
    const float* neighbor_w  = (const float*)d_in[11];
    const float* neighbor_b  = (const float*)d_in[12];
    const float* gate_w      = (const float*)d_in[13];
    const float* gate_b      = (const float*)d_in[14];
    const float* final_bias  = (const float*)d_in[15];
    const int*   edge_index  = (const int*)d_in[16];
    const int*   deprel_edge = (const int*)d_in[17];
    const int*   deparc_edge = (const int*)d_in[18];
    const int* srcArr = edge_index;
    const int* tgtArr = edge_index + N_EDGES;
    float* out = (float*)d_out;

    // workspace carve
    __half* valh = (__half*)d_ws;                                 // 10.24 MB
    unsigned short* Bt = (unsigned short*)(valh + 5120000);       // 160 KB
    float* bg2 = (float*)(Bt + 81920);                            // 8
    float* vs = bg2 + 8;
    float* vt = vs + 160000;
    float* g1 = vt + 160000;
    float* g2 = g1 + 160000;
    float* SA = g2 + 160000;
    float* SB = SA + 400;
    float* pw = SB + 32;                                          // 15.36 MB
    int* cnts = (int*)(pw + (size_t)N_EDGES * 24);                // 160,000
    int* rowptr = cnts + 160000;                                  // 20,001
    int* eidx   = rowptr + (N_NODES + 1);                         // 160,000

    k_foldrel<<<273, 256, 0, stream>>>(W_value, neighbor_w, neighbor_b,
                                       w_src, w_tgt, gate_w, Bt, bg2,
                                       W_relation, w_rel, deprel_emb, deparc_emb, SA, SB);
    k_mfma<<<N_NODES / 16, 256, 0, stream>>>(inp, Bt, bg2, valh, vs, vt, g1, g2);
    k_count2<<<dim3(8, 80), 256, 0, stream>>>(tgtArr, cnts);
    k_escore<<<N_EDGES / 256, 256, 0, stream>>>(vs, vt, SA, SB, g2, srcArr, tgtArr,
                                                deprel_edge, deparc_edge, pw);
    k_scan2<<<1, 1024, 0, stream>>>(cnts, rowptr);
    k_fill2<<<dim3(8, 80), 256, 0, stream>>>(tgtArr, rowptr, cnts, eidx);
    k_agg<<<N_NODES / 4, 256, 0, stream>>>(valh, pw, g1, rowptr, eidx, srcArr,
                                           fpw, fpb, gate_b, final_bias, out);
}

// Round 8
// 246.589 us; speedup vs baseline: 3.0486x; 1.0795x over previous
//
#include <hip/hip_runtime.h>
#include <hip/hip_fp16.h>
#include <math.h>

#define N_NODES 20000
#define N_EDGES 160000
#define EPSV 1e-12f
#define SLOPE 0.2f
#define LOG2E 1.4426950408889634f

__device__ __forceinline__ float leaky(float x) { return x >= 0.f ? x : SLOPE * x; }

__device__ __forceinline__ unsigned short cvt_bf16(float f) {
    unsigned u = __float_as_uint(f);
    u = (u + 0x7FFFu + ((u >> 16) & 1u)) >> 16;
    return (unsigned short)u;
}
__device__ __forceinline__ unsigned pk2(float a, float b) {
    return (unsigned)cvt_bf16(a) | ((unsigned)cvt_bf16(b) << 16);
}

typedef __attribute__((ext_vector_type(8))) short bf16x8;
typedef __attribute__((ext_vector_type(4))) float f32x4;

// ============ STAGE 1: fold (0..271) + rel (272) + count (273..912) ============
__global__ __launch_bounds__(256) void k_pre(
    const float* __restrict__ Wv, const float* __restrict__ Wn,
    const float* __restrict__ nbb, const float* __restrict__ wsrc,
    const float* __restrict__ wtgt, const float* __restrict__ gw,
    unsigned short* __restrict__ Bt, float* __restrict__ bg2,
    const float* __restrict__ Wrel, const float* __restrict__ wrel,
    const float* __restrict__ deprel_emb, const float* __restrict__ deparc_emb,
    float* __restrict__ SA, float* __restrict__ SB,
    const int* __restrict__ tgt, int* __restrict__ cnts)
{
    __shared__ float wr2[128 * 8];
    __shared__ int cnt[250];
    int k = threadIdx.x;
    int b = blockIdx.x;
    if (b < 256) {
        Bt[b * 256 + k] = cvt_bf16(Wv[k * 256 + b]);
    } else if (b < 264) {
        int h = b - 256;
        float a_vs = 0.f, a_vt = 0.f, a_ng = 0.f;
        for (int d = 0; d < 32; ++d) {
            float w = Wv[k * 256 + h * 32 + d];
            a_vs = fmaf(w, wsrc[h * 32 + d], a_vs);
            a_vt = fmaf(w, wtgt[h * 32 + d], a_vt);
        }
        for (int j = 0; j < 256; ++j)
            a_ng = fmaf(Wn[k * 256 + j], gw[(256 + j) * 8 + h], a_ng);
        Bt[(256 + h) * 256 + k] = cvt_bf16(a_vs);
        Bt[(264 + h) * 256 + k] = cvt_bf16(a_vt);
        Bt[(272 + h) * 256 + k] = cvt_bf16(gw[k * 8 + h]);
        Bt[(280 + h) * 256 + k] = cvt_bf16(a_ng);
        if (k == 0) {
            float s = 0.f;
            for (int j = 0; j < 256; ++j) s = fmaf(nbb[j], gw[(256 + j) * 8 + h], s);
            bg2[h] = s;
        }
    } else if (b < 272) {
        int n0 = 288 + (b - 264) * 4;
        for (int i = 0; i < 4; ++i) Bt[(n0 + i) * 256 + k] = 0;
    } else if (b == 272) {
        for (int i = k; i < 1024; i += 256) {
            int kk = i >> 3, h = i & 7;
            float acc = 0.f;
            for (int r = 0; r < 16; ++r)
                acc += Wrel[kk * 128 + h * 16 + r] * wrel[h * 16 + r];
            wr2[kk * 8 + h] = acc;
        }
        __syncthreads();
        for (int i = k; i < 50 * 8; i += 256) {
            int d = i >> 3, h = i & 7;
            float acc = 0.f;
            for (int kk = 0; kk < 64; ++kk) acc += deprel_emb[d * 64 + kk] * wr2[kk * 8 + h];
            SA[i] = acc;
        }
        for (int i = k; i < 4 * 8; i += 256) {
            int d = i >> 3, h = i & 7;
            float acc = 0.f;
            for (int kk = 0; kk < 64; ++kk) acc += deparc_emb[d * 64 + kk] * wr2[(64 + kk) * 8 + h];
            SB[i] = acc;
        }
    } else {
        int idx = b - 273;            // 0..639
        int slice = idx & 7, range = idx >> 3;
        int lo = range * 250;
        if (k < 250) cnt[k] = 0;
        __syncthreads();
        const int4* t4 = (const int4*)tgt;
        int i0 = slice * 5000;
#pragma unroll 4
        for (int i = k; i < 5000; i += 256) {
            int4 v = t4[i0 + i];
            unsigned a = (unsigned)(v.x - lo); if (a < 250u) atomicAdd(&cnt[a], 1);
            unsigned bb = (unsigned)(v.y - lo); if (bb < 250u) atomicAdd(&cnt[bb], 1);
            unsigned c = (unsigned)(v.z - lo); if (c < 250u) atomicAdd(&cnt[c], 1);
            unsigned d = (unsigned)(v.w - lo); if (d < 250u) atomicAdd(&cnt[d], 1);
        }
        __syncthreads();
        if (k < 250) cnts[(lo + k) * 8 + slice] = cnt[k];
    }
}

// ============ STAGE 2: mfma (0..1249) + scan (1250) ============
__global__ __launch_bounds__(256) void k_mid(
    const float* __restrict__ inp, const unsigned short* __restrict__ Bt,
    const float* __restrict__ bg2, __half* __restrict__ valh,
    float* __restrict__ vs, float* __restrict__ vt,
    float* __restrict__ g1, float* __restrict__ g2,
    const int* __restrict__ cnts, int* __restrict__ rowptr)
{
    __shared__ unsigned short degl[N_NODES];  // 40 KB (scan block only)
    __shared__ int wsum[4];
    int tid = threadIdx.x;
    if (blockIdx.x < 1250) {
        int wave = tid >> 6, lane = tid & 63;
        int quad = lane >> 4, l16 = lane & 15;
        int row0 = blockIdx.x * 16;
        const float* arow = inp + (size_t)(row0 + l16) * 256;
        bf16x8 afr[8];
#pragma unroll
        for (int kk = 0; kk < 8; ++kk) {
            float4 f0 = *(const float4*)(arow + kk * 32 + quad * 8);
            float4 f1 = *(const float4*)(arow + kk * 32 + quad * 8 + 4);
            union { unsigned u[4]; bf16x8 v; } cv;
            cv.u[0] = pk2(f0.x, f0.y); cv.u[1] = pk2(f0.z, f0.w);
            cv.u[2] = pk2(f1.x, f1.y); cv.u[3] = pk2(f1.z, f1.w);
            afr[kk] = cv.v;
        }
        f32x4 acc[5] = {};
        const unsigned short* bbase = Bt + (size_t)(wave * 80 + l16) * 256 + quad * 8;
#pragma unroll
        for (int kk = 0; kk < 8; ++kk) {
#pragma unroll
            for (int t = 0; t < 5; ++t) {
                bf16x8 bf = *(const bf16x8*)(bbase + t * 16 * 256 + kk * 32);
                acc[t] = __builtin_amdgcn_mfma_f32_16x16x32_bf16(afr[kk], bf, acc[t], 0, 0, 0);
            }
        }
#pragma unroll
        for (int t = 0; t < 5; ++t) {
            int n = wave * 80 + t * 16 + l16;
#pragma unroll
            for (int r = 0; r < 4; ++r) {
                int row = row0 + quad * 4 + r;
                float v = acc[t][r];
                if (n < 256) {
                    valh[(size_t)row * 256 + n] = __float2half(v);
                } else if (n < 288) {
                    int c2 = n - 256, which = c2 >> 3, h = c2 & 7;
                    if (which == 3) v += bg2[h];
                    float* dst = (which == 0) ? vs : (which == 1) ? vt : (which == 2) ? g1 : g2;
                    dst[(size_t)row * 8 + h] = v;
                }
            }
        }
    } else {
        // 256-thread scan: deg sums -> exclusive rowptr
        int lane = tid & 63, w = tid >> 6;
        for (int nn = tid; nn < N_NODES; nn += 256) {
            const int4* c4 = (const int4*)(cnts + (size_t)nn * 8);
            int4 a = c4[0], b = c4[1];
            degl[nn] = (unsigned short)(a.x + a.y + a.z + a.w + b.x + b.y + b.z + b.w);
        }
        __syncthreads();
        int start = tid * 79;
        int stop = min(start + 79, N_NODES);
        int s = 0;
        for (int i = start; i < stop; ++i) s += degl[i];
        int ps = s;
#pragma unroll
        for (int off = 1; off < 64; off <<= 1) {
            int x = __shfl_up(ps, off, 64);
            if (lane >= off) ps += x;
        }
        if (lane == 63) wsum[w] = ps;
        __syncthreads();
        if (tid == 0) {
            int a0 = wsum[0], a1 = wsum[1], a2 = wsum[2];
            wsum[0] = 0; wsum[1] = a0; wsum[2] = a0 + a1; wsum[3] = a0 + a1 + a2;
        }
        __syncthreads();
        int run = wsum[w] + ps - s;
        for (int i = start; i < stop; ++i) {
            rowptr[i] = run;
            run += degl[i];
        }
        if (tid == 255) rowptr[N_NODES] = run;
    }
}

// ============ STAGE 3: escore (0..624) + fill (625..1264) ============
__global__ __launch_bounds__(256) void k_post(
    const float* __restrict__ vs, const float* __restrict__ vt,
    const float* __restrict__ SA, const float* __restrict__ SB,
    const float* __restrict__ g2,
    const int* __restrict__ src, const int* __restrict__ tgt,
    const int* __restrict__ deprel, const int* __restrict__ deparc,
    float* __restrict__ pw,
    const int* __restrict__ rowptr, const int* __restrict__ cnts,
    int* __restrict__ eidx)
{
    __shared__ int cur[250];
    int tid = threadIdx.x;
    if (blockIdx.x < 625) {
        int e = blockIdx.x * 256 + tid;
        int s = src[e], t = tgt[e], dr = deprel[e], da = deparc[e];
        const float4* vs4 = (const float4*)(vs + (size_t)s * 8);
        const float4* vt4 = (const float4*)(vt + (size_t)t * 8);
        const float4* SA4 = (const float4*)(SA + dr * 8);
        const float4* SB4 = (const float4*)(SB + da * 8);
        const float4* g24 = (const float4*)(g2 + (size_t)s * 8);
        float4 a0 = vs4[0], a1 = vs4[1];
        float4 b0 = vt4[0], b1 = vt4[1];
        float4 ra0 = SA4[0], ra1 = SA4[1];
        float4 rb0 = SB4[0], rb1 = SB4[1];
        float4 gg0 = g24[0], gg1 = g24[1];
        float av[8] = {a0.x, a0.y, a0.z, a0.w, a1.x, a1.y, a1.z, a1.w};
        float bv[8] = {b0.x, b0.y, b0.z, b0.w, b1.x, b1.y, b1.z, b1.w};
        float rv[8] = {ra0.x + rb0.x, ra0.y + rb0.y, ra0.z + rb0.z, ra0.w + rb0.w,
                       ra1.x + rb1.x, ra1.y + rb1.y, ra1.z + rb1.z, ra1.w + rb1.w};
        float ev[8], er[8];
#pragma unroll
        for (int h = 0; h < 8; ++h) {
            ev[h] = exp2f(leaky(av[h] + bv[h]) * LOG2E);
            er[h] = exp2f(leaky(rv[h] + bv[h]) * LOG2E);
        }
        float4* o = (float4*)(pw + (size_t)e * 24);
        o[0] = make_float4(ev[0], ev[1], ev[2], ev[3]);
        o[1] = make_float4(ev[4], ev[5], ev[6], ev[7]);
        o[2] = make_float4(er[0], er[1], er[2], er[3]);
        o[3] = make_float4(er[4], er[5], er[6], er[7]);
        o[4] = gg0;
        o[5] = gg1;
    } else {
        int idx = blockIdx.x - 625;
        int slice = idx & 7, range = idx >> 3;
        int lo = range * 250;
        if (tid < 250) {
            int base = rowptr[lo + tid];
            const int* c = cnts + (size_t)(lo + tid) * 8;
            for (int s = 0; s < slice; ++s) base += c[s];
            cur[tid] = base;
        }
        __syncthreads();
        const int4* t4 = (const int4*)tgt;
        int i0 = slice * 5000;
        for (int i = tid; i < 5000; i += 256) {
            int4 v = t4[i0 + i];
            int e = (i0 + i) * 4;
            unsigned a = (unsigned)(v.x - lo); if (a < 250u) { int p = atomicAdd(&cur[a], 1); eidx[p] = e; }
            unsigned b = (unsigned)(v.y - lo); if (b < 250u) { int p = atomicAdd(&cur[b], 1); eidx[p] = e + 1; }
            unsigned c = (unsigned)(v.z - lo); if (c < 250u) { int p = atomicAdd(&cur[c], 1); eidx[p] = e + 2; }
            unsigned d = (unsigned)(v.w - lo); if (d < 250u) { int p = atomicAdd(&cur[d], 1); eidx[p] = e + 3; }
        }
    }
}

// ============ STAGE 4: per-node aggregation, R6 layout + unroll-2 prefetch ============
__global__ __launch_bounds__(256) void k_agg(
    const __half* __restrict__ valh, const float* __restrict__ pw,
    const float* __restrict__ g1,
    const int* __restrict__ rowptr, const int* __restrict__ eidx,
    const int* __restrict__ srcArr,
    const float* __restrict__ Wp, const float* __restrict__ Pb,
    const float* __restrict__ gate_b, const float* __restrict__ final_bias,
    float* __restrict__ out)
{
    __shared__ float cat[4][548];
    __shared__ float gate_lds[4][8];
    int tid = threadIdx.x, wv = tid >> 6, l = tid & 63;
    int n = blockIdx.x * 4 + wv;
    int beg = rowptr[n], end = rowptr[n + 1];
    int deg = end - beg;
    int h8 = l >> 3;
    int q = l & 7;

    float acc = 0.f;
    float4 av = make_float4(0, 0, 0, 0), ar = make_float4(0, 0, 0, 0);

    for (int base = beg; base < end; base += 64) {
        int cnt = min(64, end - base);
        int epre = 0, spre = 0;
        if (l < cnt) { epre = eidx[base + l]; spre = srcArr[epre]; }
        float pw0, pw1;
        uint2 v0, v1;
        {
            int e0 = __shfl(epre, 0, 64), s0 = __shfl(spre, 0, 64);
            pw0 = (l < 24) ? pw[(size_t)e0 * 24 + l] : 0.f;
            v0 = *(const uint2*)(valh + (size_t)s0 * 256 + l * 4);
            int j1 = (cnt > 1) ? 1 : 0;
            int e1 = __shfl(epre, j1, 64), s1 = __shfl(spre, j1, 64);
            pw1 = (l < 24) ? pw[(size_t)e1 * 24 + l] : 0.f;
            v1 = *(const uint2*)(valh + (size_t)s1 * 256 + l * 4);
        }
        for (int j = 0; j < cnt; j += 2) {
            float pa = pw0; uint2 va = v0;
            float pb = pw1; uint2 vb = v1;
            if (j + 2 < cnt) {
                int j3 = (j + 3 < cnt) ? j + 3 : j + 2;
                int e2 = __shfl(epre, j + 2, 64), s2 = __shfl(spre, j + 2, 64);
                int e3 = __shfl(epre, j3, 64), s3 = __shfl(spre, j3, 64);
                pw0 = (l < 24) ? pw[(size_t)e2 * 24 + l] : 0.f;
                v0 = *(const uint2*)(valh + (size_t)s2 * 256 + l * 4);
                pw1 = (l < 24) ? pw[(size_t)e3 * 24 + l] : 0.f;
                v1 = *(const uint2*)(valh + (size_t)s3 * 256 + l * 4);
            }
            {
                float tmp = pa;
                if (l < 24) acc += tmp;
                float wV = __shfl(tmp, h8, 64);
                float wR = __shfl(tmp, 8 + h8, 64);
                float2 f0 = __half22float2(*(__half2*)&va.x);
                float2 f1 = __half22float2(*(__half2*)&va.y);
                av.x = fmaf(f0.x, wV, av.x); av.y = fmaf(f0.y, wV, av.y);
                av.z = fmaf(f1.x, wV, av.z); av.w = fmaf(f1.y, wV, av.w);
                ar.x = fmaf(f0.x, wR, ar.x); ar.y = fmaf(f0.y, wR, ar.y);
                ar.z = fmaf(f1.x, wR, ar.z); ar.w = fmaf(f1.y, wR, ar.w);
            }
            if (j + 1 < cnt) {
                float tmp = pb;
                if (l < 24) acc += tmp;
                float wV = __shfl(tmp, h8, 64);
                float wR = __shfl(tmp, 8 + h8, 64);
                float2 f0 = __half22float2(*(__half2*)&vb.x);
                float2 f1 = __half22float2(*(__half2*)&vb.y);
                av.x = fmaf(f0.x, wV, av.x); av.y = fmaf(f0.y, wV, av.y);
                av.z = fmaf(f1.x, wV, av.z); av.w = fmaf(f1.y, wV, av.w);
                ar.x = fmaf(f0.x, wR, ar.x); ar.y = fmaf(f0.y, wR, ar.y);
                ar.z = fmaf(f1.x, wR, ar.z); ar.w = fmaf(f1.y, wR, ar.w);
            }
        }
    }
    float dv = __shfl(acc, h8, 64) + EPSV;
    float drn = __shfl(acc, 8 + h8, 64) + EPSV;
    float rdv = 1.f / dv, rdr = 1.f / drn;
    av.x *= rdv; av.y *= rdv; av.z *= rdv; av.w *= rdv;
    ar.x *= rdr; ar.y *= rdr; ar.z *= rdr; ar.w *= rdr;

    float* cp = &cat[wv][h8 * 68 + q * 4];
    *(float4*)cp = av;
    *(float4*)(cp + 32) = ar;

    float dscale = 1.f / (float)(deg > 1 ? deg : 1);
    float gs = __shfl(acc, 16 + q, 64);
    if (l < 8) {
        float gl = g1[(size_t)n * 8 + l] + gs * dscale + gate_b[l];
        gate_lds[wv][l] = 1.f / (1.f + exp2f(-gl * LOG2E));
    }
    __syncthreads();

    int nd = tid & 3, oi = tid >> 2;
    int hh = oi >> 3, qq = oi & 7;
    float4 ho = *(const float4*)(Pb + oi * 4);
    const float* crow = &cat[nd][hh * 68];
    const float* wrow = Wp + (size_t)hh * 2048 + qq * 4;
#pragma unroll 4
    for (int d = 0; d < 64; ++d) {
        float c = crow[d];
        float4 w4 = *(const float4*)(wrow + d * 32);
        ho.x = fmaf(c, w4.x, ho.x); ho.y = fmaf(c, w4.y, ho.y);
        ho.z = fmaf(c, w4.z, ho.z); ho.w = fmaf(c, w4.w, ho.w);
    }
    float g = gate_lds[nd][hh];
    float4 fb = *(const float4*)(final_bias + oi * 4);
    float4 o;
    o.x = fmaf(ho.x, g, fb.x); o.y = fmaf(ho.y, g, fb.y);
    o.z = fmaf(ho.z, g, fb.z); o.w = fmaf(ho.w, g, fb.w);
    *(float4*)(out + (size_t)(blockIdx.x * 4 + nd) * 256 + oi * 4) = o;
}

extern "C" void kernel_launch(void* const* d_in, const int* in_sizes, int n_in,
                              void* d_out, int out_size, void* d_ws, size_t ws_size,
                              hipStream_t stream) {
    const float* inp         = (const float*)d_in[0];
    const float* W_value     = (const float*)d_in[2];
    const float* W_relation  = (const float*)d_in[3];
    const float* deprel_emb  = (const float*)d_in[4];
    const float* deparc_emb  = (const float*)d_in[5];
    const float* w_src       = (const float*)d_in[6];
    const float* w_tgt       = (const float*)d_in[7];
    const float* w_rel       = (const float*)d_in[8];
    const float* fpw         = (const float*)d_in[9];
    const float* fpb         = (const float*)d_in[10];
    const float* neighbor_w  = (const float*)d_in[11];
    const float* neighbor_b  = (const float*)d_in[12];
    const float* gate_w      = (const float*)d_in[13];
    const float* gate_b      = (const float*)d_in[14];
    const float* final_bias  = (const float*)d_in[15];
    const int*   edge_index  = (const int*)d_in[16];
    const int*   deprel_edge = (const int*)d_in[17];
    const int*   deparc_edge = (const int*)d_in[18];
    const int* srcArr = edge_index;
    const int* tgtArr = edge_index + N_EDGES;
    float* out = (float*)d_out;

    // workspace carve
    __half* valh = (__half*)d_ws;                                 // 10.24 MB
    unsigned short* Bt = (unsigned short*)(valh + 5120000);       // 160 KB
    float* bg2 = (float*)(Bt + 81920);                            // 8
    float* vs = bg2 + 8;
    float* vt = vs + 160000;
    float* g1 = vt + 160000;
    float* g2 = g1 + 160000;
    float* SA = g2 + 160000;
    float* SB = SA + 400;
    float* pw = SB + 32;                                          // 15.36 MB
    int* cnts = (int*)(pw + (size_t)N_EDGES * 24);                // 160,000
    int* rowptr = cnts + 160000;                                  // 20,001
    int* eidx   = rowptr + (N_NODES + 1);                         // 160,000

    k_pre<<<913, 256, 0, stream>>>(W_value, neighbor_w, neighbor_b,
                                   w_src, w_tgt, gate_w, Bt, bg2,
                                   W_relation, w_rel, deprel_emb, deparc_emb, SA, SB,
                                   tgtArr, cnts);
    k_mid<<<1251, 256, 0, stream>>>(inp, Bt, bg2, valh, vs, vt, g1, g2, cnts, rowptr);
    k_post<<<1265, 256, 0, stream>>>(vs, vt, SA, SB, g2, srcArr, tgtArr,
                                     deprel_edge, deparc_edge, pw, rowptr, cnts, eidx);
    k_agg<<<N_NODES / 4, 256, 0, stream>>>(valh, pw, g1, rowptr, eidx, srcArr,
                                           fpw, fpb, gate_b, final_bias, out);
}